// Round 7
// baseline (1936.826 us; speedup 1.0000x reference)
//
#include <hip/hip_runtime.h>
#include <hip/hip_fp16.h>
#include <cstdint>

#define T_LEN 2048
#define NTOK  4096      // B*T
#define NHASH 8
#define SELF_VAL -5e4f
#define SPLIT_S 2048.f
#define SPLIT_IS (1.f/2048.f)

typedef __attribute__((ext_vector_type(8))) short short8v;
typedef __attribute__((ext_vector_type(8))) _Float16 half8v;
typedef __attribute__((ext_vector_type(4))) float f32x4;
typedef __attribute__((ext_vector_type(4))) unsigned short ushort4v;

__device__ inline void split16(float v, __half& h1, __half& h2) {
  h1 = __float2half(v);
  h2 = __float2half((v - __half2float(h1)) * SPLIT_S);
}

// ---------------------------------------------------------------- im2col split-f16 (conv k=3 pad=1), K padded to 704
__global__ __launch_bounds__(256) void k_im2col2(
    const float* __restrict__ spec, __half* __restrict__ c1, __half* __restrict__ c2) {
  int m = blockIdx.x; int b = m >> 11, t = m & 2047;
  for (int c = threadIdx.x; c < 704; c += 256) {
    float v = 0.f;
    if (c < 687) {
      int k = (c >= 458) ? 2 : (c >= 229 ? 1 : 0);
      int i = c - k * 229;
      int tt = t + k - 1;
      if (tt >= 0 && tt < T_LEN) v = spec[((long)b * T_LEN + tt) * 229 + i];
    }
    __half h1, h2; split16(v, h1, h2);
    c1[(long)m * 704 + c] = h1; c2[(long)m * 704 + c] = h2;
  }
}

// conv weight split, Bt layout [o][c=k*229+i], c padded to 704
__global__ __launch_bounds__(256) void k_wconv2(
    const float* __restrict__ w, __half* __restrict__ d1, __half* __restrict__ d2) {
  int o = blockIdx.x;
  for (int c = threadIdx.x; c < 704; c += 256) {
    float v = 0.f;
    if (c < 687) {
      int k = (c >= 458) ? 2 : (c >= 229 ? 1 : 0);
      int i = c - k * 229;
      v = w[((long)o * 229 + i) * 3 + k];
    }
    __half h1, h2; split16(v, h1, h2);
    d1[(long)o * 704 + c] = h1; d2[(long)o * 704 + c] = h2;
  }
}

__global__ __launch_bounds__(256) void k_pe(
    const float* __restrict__ pe_row, const float* __restrict__ pe_col,
    float* __restrict__ x1, float* __restrict__ x2) {
  int m = blockIdx.x, t = m & 2047;
  for (int o = threadIdx.x; o < 512; o += 256) {
    long idx = (long)m * 512 + o;
    float v = x1[idx] + ((o < 256) ? pe_row[(t >> 6) * 256 + o]
                                   : pe_col[(t & 63) * 256 + (o - 256)]);
    x1[idx] = v; x2[idx] = v;
  }
}

// ---------------------------------------------------------------- layernorm; SPLIT: also emit scaled f16 correction
template<int SPLIT>
__global__ __launch_bounds__(256) void k_ln(
    const float* __restrict__ x, const float* __restrict__ g,
    const float* __restrict__ bb, __half* __restrict__ o1, __half* __restrict__ o2) {
  int row = blockIdx.x, tid = threadIdx.x;
  const float* xr = x + (long)row * 512;
  float v0 = xr[tid], v1 = xr[tid + 256];
  float s1 = v0 + v1, s2 = v0 * v0 + v1 * v1;
  #pragma unroll
  for (int off = 1; off < 64; off <<= 1) { s1 += __shfl_xor(s1, off); s2 += __shfl_xor(s2, off); }
  __shared__ float r1[4], r2[4];
  int w = tid >> 6, lane = tid & 63;
  if (lane == 0) { r1[w] = s1; r2[w] = s2; }
  __syncthreads();
  float S1 = r1[0] + r1[1] + r1[2] + r1[3];
  float S2 = r2[0] + r2[1] + r2[2] + r2[3];
  float mean = S1 * (1.f / 512.f);
  float var  = S2 * (1.f / 512.f) - mean * mean;
  float rstd = 1.f / sqrtf(var + 1e-5f);
  float a0 = (v0 - mean) * rstd * g[tid] + bb[tid];
  float a1 = (v1 - mean) * rstd * g[tid + 256] + bb[tid + 256];
  if (SPLIT) {
    __half h1, h2;
    split16(a0, h1, h2); o1[(long)row * 512 + tid] = h1; o2[(long)row * 512 + tid] = h2;
    split16(a1, h1, h2); o1[(long)row * 512 + tid + 256] = h1; o2[(long)row * 512 + tid + 256] = h2;
  } else {
    o1[(long)row * 512 + tid]       = __float2half(a0);
    o1[(long)row * 512 + tid + 256] = __float2half(a1);
  }
}

// 0.5*(x1+x2) -> split f16
__global__ __launch_bounds__(256) void k_halfcvt(
    const float* __restrict__ x1, const float* __restrict__ x2,
    __half* __restrict__ a1, __half* __restrict__ a2) {
  long idx = (long)blockIdx.x * 512 + threadIdx.x;
  #pragma unroll
  for (int rep = 0; rep < 2; ++rep, idx += 256) {
    float v = 0.5f * (x1[idx] + x2[idx]);
    __half h1, h2; split16(v, h1, h2);
    a1[idx] = h1; a2[idx] = h2;
  }
}

// ---------------------------------------------------------------- split-f16 MFMA GEMM (f32-grade): qk/conv/lin
// C = (A1 + A2/S) @ (B1 + B2/S)^T, dropping A2B2. 64x64 tile, BK=64, 1D grid + XCD swizzle.
template<int MAP, int BIAS, int RELU, int NG>
__global__ __launch_bounds__(256) void k_mgemm2(
    const ushort* __restrict__ A1, const ushort* __restrict__ A2,
    const ushort* __restrict__ B1, const ushort* __restrict__ B2,
    const float* __restrict__ bias, float* __restrict__ C,
    int M, int N, int K, int ncol, int Nreal) {
  __shared__ ushort As1[64 * 72], As2[64 * 72], Bs1[64 * 72], Bs2[64 * 72];
  int tid = threadIdx.x;
  int nwg = gridDim.x, q8 = nwg >> 3, wg = blockIdx.x;
  int swz = (wg & 7) * q8 + (wg >> 3);
  int m0 = (swz / ncol) * 64, n0 = (swz % ncol) * 64;
  int wid = tid >> 6, lane = tid & 63;
  int wr = wid >> 1, wc = wid & 1;
  int r = lane & 15, kg = lane >> 4;
  f32x4 accM[2][2] = {}, accC[2][2] = {};
  for (int k0 = 0; k0 < K; k0 += 64) {
    __syncthreads();
    #pragma unroll
    for (int rep = 0; rep < 2; ++rep) {
      int idx = tid + rep * 256;
      int ar_ = idx >> 3, ac_ = idx & 7;
      *(short8v*)&As1[ar_ * 72 + ac_ * 8] = *(const short8v*)(A1 + (long)(m0 + ar_) * K + k0 + ac_ * 8);
      *(short8v*)&As2[ar_ * 72 + ac_ * 8] = *(const short8v*)(A2 + (long)(m0 + ar_) * K + k0 + ac_ * 8);
      *(short8v*)&Bs1[ar_ * 72 + ac_ * 8] = *(const short8v*)(B1 + (long)(n0 + ar_) * K + k0 + ac_ * 8);
      *(short8v*)&Bs2[ar_ * 72 + ac_ * 8] = *(const short8v*)(B2 + (long)(n0 + ar_) * K + k0 + ac_ * 8);
    }
    __syncthreads();
    #pragma unroll
    for (int ks = 0; ks < 2; ++ks) {
      half8v a1[2], a2[2], b1[2], b2[2];
      #pragma unroll
      for (int i = 0; i < 2; ++i) {
        a1[i] = *(const half8v*)&As1[(wr * 32 + i * 16 + r) * 72 + ks * 32 + kg * 8];
        a2[i] = *(const half8v*)&As2[(wr * 32 + i * 16 + r) * 72 + ks * 32 + kg * 8];
      }
      #pragma unroll
      for (int j = 0; j < 2; ++j) {
        b1[j] = *(const half8v*)&Bs1[(wc * 32 + j * 16 + r) * 72 + ks * 32 + kg * 8];
        b2[j] = *(const half8v*)&Bs2[(wc * 32 + j * 16 + r) * 72 + ks * 32 + kg * 8];
      }
      #pragma unroll
      for (int i = 0; i < 2; ++i)
        #pragma unroll
        for (int j = 0; j < 2; ++j) {
          accM[i][j] = __builtin_amdgcn_mfma_f32_16x16x32_f16(a1[i], b1[j], accM[i][j], 0, 0, 0);
          accC[i][j] = __builtin_amdgcn_mfma_f32_16x16x32_f16(a1[i], b2[j], accC[i][j], 0, 0, 0);
          accC[i][j] = __builtin_amdgcn_mfma_f32_16x16x32_f16(a2[i], b1[j], accC[i][j], 0, 0, 0);
        }
    }
  }
  #pragma unroll
  for (int i = 0; i < 2; ++i) {
    int mb = m0 + wr * 32 + i * 16 + kg * 4;
    #pragma unroll
    for (int j = 0; j < 2; ++j) {
      int n = n0 + wc * 32 + j * 16 + r;
      if (NG && n >= Nreal) continue;
      float bv = BIAS ? bias[n] : 0.f;
      #pragma unroll
      for (int q = 0; q < 4; ++q) {
        float v = accM[i][j][q] + accC[i][j][q] * SPLIT_IS + bv;
        if (RELU) v = fmaxf(v, 0.f);
        long idx;
        if (MAP == 1) {
          int m = mb + q;
          int b = m >> 11, t = m & 2047, hh = n >> 6, dd = n & 63;
          idx = (((long)(b * 8 + hh)) * T_LEN + t) * 64 + dd;
        } else {
          idx = (long)(mb + q) * Nreal + n;
        }
        C[idx] = v;
      }
    }
  }
}

// ---------------------------------------------------------------- f16 MFMA GEMM (v/wo/FFN), 64x64 tile, BK=64
template<int MAP, int BIAS, int GELU, int RES>
__global__ __launch_bounds__(256) void k_mgemm(
    const ushort* __restrict__ A, const ushort* __restrict__ Bt,
    const float* __restrict__ bias, __half* __restrict__ Ch,
    float* __restrict__ Cf, int M, int N, int K, int ncol) {
  __shared__ ushort As[64 * 72];
  __shared__ ushort Bs[64 * 72];
  int tid = threadIdx.x;
  int nwg = gridDim.x, q8 = nwg >> 3, wg = blockIdx.x;
  int swz = (wg & 7) * q8 + (wg >> 3);
  int m0 = (swz / ncol) * 64, n0 = (swz % ncol) * 64;
  int wid = tid >> 6, lane = tid & 63;
  int wr = wid >> 1, wc = wid & 1;
  int r = lane & 15, kg = lane >> 4;
  f32x4 acc[2][2] = {};
  for (int k0 = 0; k0 < K; k0 += 64) {
    __syncthreads();
    #pragma unroll
    for (int rep = 0; rep < 2; ++rep) {
      int idx = tid + rep * 256;
      int ar_ = idx >> 3, ac_ = idx & 7;
      *(short8v*)&As[ar_ * 72 + ac_ * 8] =
          *(const short8v*)(A + (long)(m0 + ar_) * K + k0 + ac_ * 8);
      *(short8v*)&Bs[ar_ * 72 + ac_ * 8] =
          *(const short8v*)(Bt + (long)(n0 + ar_) * K + k0 + ac_ * 8);
    }
    __syncthreads();
    #pragma unroll
    for (int ks = 0; ks < 2; ++ks) {
      half8v af[2], bf[2];
      #pragma unroll
      for (int i = 0; i < 2; ++i)
        af[i] = *(const half8v*)&As[(wr * 32 + i * 16 + r) * 72 + ks * 32 + kg * 8];
      #pragma unroll
      for (int j = 0; j < 2; ++j)
        bf[j] = *(const half8v*)&Bs[(wc * 32 + j * 16 + r) * 72 + ks * 32 + kg * 8];
      #pragma unroll
      for (int i = 0; i < 2; ++i)
        #pragma unroll
        for (int j = 0; j < 2; ++j)
          acc[i][j] = __builtin_amdgcn_mfma_f32_16x16x32_f16(af[i], bf[j], acc[i][j], 0, 0, 0);
    }
  }
  #pragma unroll
  for (int i = 0; i < 2; ++i) {
    int mb = m0 + wr * 32 + i * 16 + kg * 4;
    #pragma unroll
    for (int j = 0; j < 2; ++j) {
      int n = n0 + wc * 32 + j * 16 + r;
      float bv = BIAS ? bias[n] : 0.f;
      #pragma unroll
      for (int q = 0; q < 4; ++q) {
        float v = acc[i][j][q] + bv;
        if (GELU) v = 0.5f * v * (1.f + erff(v * 0.70710678118654752f));
        long idx;
        if (MAP == 1) {
          int m = mb + q;
          int b = m >> 11, t = m & 2047, hh = n >> 6, dd = n & 63;
          idx = (((long)(b * 8 + hh)) * T_LEN + t) * 64 + dd;
        } else {
          idx = (long)(mb + q) * N + n;
        }
        if (RES) Cf[idx] += v;
        else Ch[idx] = __float2half(v);
      }
    }
  }
}

// tiled transpose + f32->f16 (single): dst[c][r] = h(src[r][c])
__global__ __launch_bounds__(256) void k_tcvt(
    const float* __restrict__ src, __half* __restrict__ dst, int R, int C) {
  __shared__ float tile[32][33];
  int c0 = blockIdx.x * 32, r0 = blockIdx.y * 32;
  int tx = threadIdx.x & 31, ty = threadIdx.x >> 5;
  #pragma unroll
  for (int i = 0; i < 4; ++i)
    tile[ty + i * 8][tx] = src[(long)(r0 + ty + i * 8) * C + c0 + tx];
  __syncthreads();
  #pragma unroll
  for (int i = 0; i < 4; ++i)
    dst[(long)(c0 + ty + i * 8) * R + r0 + tx] = __float2half(tile[tx][ty + i * 8]);
}

// tiled transpose + split f16 pair, col-padded: dst[c][r], c in [0,Cpad)
__global__ __launch_bounds__(256) void k_tcvt2(
    const float* __restrict__ src, __half* __restrict__ d1, __half* __restrict__ d2,
    int R, int C) {
  __shared__ float tile[32][33];
  int c0 = blockIdx.x * 32, r0 = blockIdx.y * 32;
  int tx = threadIdx.x & 31, ty = threadIdx.x >> 5;
  #pragma unroll
  for (int i = 0; i < 4; ++i) {
    int c = c0 + tx;
    tile[ty + i * 8][tx] = (c < C) ? src[(long)(r0 + ty + i * 8) * C + c] : 0.f;
  }
  __syncthreads();
  #pragma unroll
  for (int i = 0; i < 4; ++i) {
    float v = tile[tx][ty + i * 8];
    __half h1, h2; split16(v, h1, h2);
    long o = (long)(c0 + ty + i * 8) * R + r0 + tx;
    d1[o] = h1; d2[o] = h2;
  }
}

// ---------------------------------------------------------------- qk prep: normalized f16 K + f32 row norm
__global__ __launch_bounds__(256) void k_qprep(
    const float* __restrict__ qk, __half* __restrict__ kn, float* __restrict__ qnorm) {
  int row = blockIdx.x * 4 + (threadIdx.x >> 6);
  int d = threadIdx.x & 63;
  float v = qk[(long)row * 64 + d];
  float s2 = v * v;
  #pragma unroll
  for (int off = 1; off < 64; off <<= 1) s2 += __shfl_xor(s2, off);
  float nrm = fmaxf(sqrtf(s2), 1e-12f);
  kn[(long)row * 64 + d] = __float2half(v / nrm);
  if (d == 0) qnorm[row] = nrm;
}

// ---------------------------------------------------------------- LSH hashing (f32)
__global__ __launch_bounds__(256) void k_hash(
    const float* __restrict__ qk, const float* __restrict__ rot,
    int* __restrict__ buckets) {
  int bhid = blockIdx.x >> 6; int t0 = (blockIdx.x & 63) * 32;
  __shared__ float qrow[32][64];
  __shared__ float rl[64][8][20];
  for (int idx = threadIdx.x; idx < 32 * 64; idx += 256) {
    int tok = idx >> 6, f = idx & 63;
    qrow[tok][f] = qk[((long)bhid * T_LEN + t0 + tok) * 64 + f];
  }
  for (int idx = threadIdx.x; idx < 64 * 128; idx += 256) {
    int f = idx >> 7, rem = idx & 127, hh = rem >> 4, ii = rem & 15;
    rl[f][hh][ii] = rot[idx];
  }
  __syncthreads();
  int tok = threadIdx.x >> 3, h = threadIdx.x & 7;
  float acc[16] = {};
  for (int f = 0; f < 64; ++f) {
    float qv = qrow[tok][f];
    #pragma unroll
    for (int i = 0; i < 16; ++i) acc[i] += qv * rl[f][h][i];
  }
  float best = acc[0]; int bi = 0;
  #pragma unroll
  for (int i = 1; i < 16; ++i) if (acc[i] > best) { best = acc[i]; bi = i; }
  #pragma unroll
  for (int i = 0; i < 16; ++i) if (-acc[i] > best) { best = -acc[i]; bi = 16 + i; }
  buckets[((long)bhid * 8 + h) * T_LEN + t0 + tok] = bi;
}

// ---------------------------------------------------------------- stable counting sort
__global__ __launch_bounds__(256) void k_sort(
    const int* __restrict__ buckets, int* __restrict__ st) {
  int bh = blockIdx.x >> 3, h = blockIdx.x & 7;
  const int* bk = buckets + ((long)bh * 8 + h) * T_LEN;
  __shared__ unsigned char lb[2048];
  __shared__ int hist[32], cnt[32];
  __shared__ int whist[4][32];
  if (threadIdx.x < 32) hist[threadIdx.x] = 0;
  __syncthreads();
  for (int p = threadIdx.x; p < 2048; p += 256) {
    int v = bk[p]; lb[p] = (unsigned char)v; atomicAdd(&hist[v], 1);
  }
  __syncthreads();
  if (threadIdx.x == 0) {
    int run = 0;
    for (int i = 0; i < 32; ++i) { cnt[i] = run; run += hist[i]; }
  }
  __syncthreads();
  int lane = threadIdx.x & 63, w = threadIdx.x >> 6;
  unsigned long long mlt = (1ull << lane) - 1ull;
  int* outp = st + (long)bh * (NHASH * T_LEN) + h * T_LEN;
  for (int tile = 0; tile < 8; ++tile) {
    int p = tile * 256 + threadIdx.x;
    int myb = lb[p];
    int wrank = 0;
    for (int bv = 0; bv < 32; ++bv) {
      unsigned long long mm = __ballot(myb == bv);
      if (myb == bv) wrank = __popcll(mm & mlt);
      if (lane == bv) whist[w][bv] = __popcll(mm);
    }
    __syncthreads();
    int off = cnt[myb];
    for (int w2 = 0; w2 < w; ++w2) off += whist[w2][myb];
    outp[off + wrank] = p;
    __syncthreads();
    if (threadIdx.x < 32)
      cnt[threadIdx.x] += whist[0][threadIdx.x] + whist[1][threadIdx.x] +
                          whist[2][threadIdx.x] + whist[3][threadIdx.x];
    __syncthreads();
  }
}

// ---------------------------------------------------------------- MFMA chunked attention (o out f16)
// Ps aliases Kb (dead after QK^T) -> LDS ~36.6KB -> 4 blocks/CU.
__global__ __launch_bounds__(256) void k_attn_mfma(
    const ushort* __restrict__ kn, const float* __restrict__ qnorm,
    const ushort* __restrict__ vv, const int* __restrict__ st,
    __half* __restrict__ o, float* __restrict__ lg) {
  __shared__ ushort KbPs[128 * 72];   // Kb [kv][72] during QK; Ps [q][136] during PV
  __shared__ ushort Vt[64 * 136];
  __shared__ int   kpos[128];
  __shared__ float qn[64];
  int bh = blockIdx.x >> 8, c = blockIdx.x & 255;
  int h = c >> 5, cp = (c + 255) & 255;
  int tid = threadIdx.x, lane = tid & 63, w = tid >> 6;
  int r16 = lane & 15, kg = lane >> 4;
  const int* stb = st + (long)bh * (NHASH * T_LEN);
  if (tid < 128) kpos[tid] = stb[((tid < 64) ? c : cp) * 64 + (tid & 63)];
  __syncthreads();
  if (tid < 64) qn[tid] = qnorm[bh * T_LEN + kpos[tid]];
  const ushort* knb = kn + (long)bh * T_LEN * 64;
  const ushort* vvb = vv + (long)bh * T_LEN * 64;
  for (int idx = tid; idx < 1024; idx += 256) {
    int rr = idx >> 3, p = idx & 7;
    *(short8v*)&KbPs[rr * 72 + p * 8] = *(const short8v*)(knb + (long)kpos[rr] * 64 + p * 8);
  }
  {
    int rr = (tid & 63) * 2;
    ushort a[16], b[16];
    *(short8v*)&a[0] = *(const short8v*)(vvb + (long)kpos[rr] * 64 + w * 16);
    *(short8v*)&a[8] = *(const short8v*)(vvb + (long)kpos[rr] * 64 + w * 16 + 8);
    *(short8v*)&b[0] = *(const short8v*)(vvb + (long)kpos[rr + 1] * 64 + w * 16);
    *(short8v*)&b[8] = *(const short8v*)(vvb + (long)kpos[rr + 1] * 64 + w * 16 + 8);
    #pragma unroll
    for (int i = 0; i < 16; ++i) {
      int d = w * 16 + i;
      *(unsigned int*)&Vt[d * 136 + rr] = (unsigned int)a[i] | ((unsigned int)b[i] << 16);
    }
  }
  __syncthreads();
  f32x4 sacc[8] = {};
  #pragma unroll
  for (int ks = 0; ks < 2; ++ks) {
    half8v bfq = *(const half8v*)&KbPs[(w * 16 + r16) * 72 + ks * 32 + kg * 8];
    #pragma unroll
    for (int i = 0; i < 8; ++i) {
      half8v af = *(const half8v*)&KbPs[(i * 16 + r16) * 72 + ks * 32 + kg * 8];
      sacc[i] = __builtin_amdgcn_mfma_f32_16x16x32_f16(af, bfq, sacc[i], 0, 0, 0);
    }
  }
  __syncthreads();   // Kb now dead; safe to overwrite with Ps
  int q = w * 16 + r16;
  int qposv = kpos[q];
  float sc = 0.125f * qn[q];
  float vals[8][4];
  float mx = -3.4e38f;
  #pragma unroll
  for (int f = 0; f < 8; ++f)
    #pragma unroll
    for (int e = 0; e < 4; ++e) {
      int kv = f * 16 + kg * 4 + e;
      float v = sacc[f][e] * sc;
      if (kpos[kv] == qposv) v = SELF_VAL;
      vals[f][e] = v;
      mx = fmaxf(mx, v);
    }
  mx = fmaxf(mx, __shfl_xor(mx, 16));
  mx = fmaxf(mx, __shfl_xor(mx, 32));
  float sm = 0.f;
  #pragma unroll
  for (int f = 0; f < 8; ++f)
    #pragma unroll
    for (int e = 0; e < 4; ++e) { vals[f][e] = __expf(vals[f][e] - mx); sm += vals[f][e]; }
  sm += __shfl_xor(sm, 16);
  sm += __shfl_xor(sm, 32);
  float inv = 1.f / sm;
  #pragma unroll
  for (int f = 0; f < 8; ++f) {
    ushort4v pw;
    #pragma unroll
    for (int e = 0; e < 4; ++e) pw[e] = __half_as_ushort(__float2half(vals[f][e] * inv));
    *(ushort4v*)&KbPs[q * 136 + f * 16 + kg * 4] = pw;
  }
  if (kg == 0) lg[((long)bh * 8 + h) * T_LEN + qposv] = mx + logf(sm);
  __syncthreads();
  f32x4 oacc[4] = {};
  #pragma unroll
  for (int ks = 0; ks < 4; ++ks) {
    half8v vf = *(const half8v*)&Vt[(w * 16 + r16) * 136 + ks * 32 + kg * 8];
    #pragma unroll
    for (int i = 0; i < 4; ++i) {
      half8v pf = *(const half8v*)&KbPs[(i * 16 + r16) * 136 + ks * 32 + kg * 8];
      oacc[i] = __builtin_amdgcn_mfma_f32_16x16x32_f16(pf, vf, oacc[i], 0, 0, 0);
    }
  }
  long ob = ((long)bh * 8 + h) * T_LEN;
  int d = w * 16 + r16;
  #pragma unroll
  for (int i = 0; i < 4; ++i)
    #pragma unroll
    for (int e = 0; e < 4; ++e)
      o[(ob + kpos[i * 16 + kg * 4 + e]) * 64 + d] = __float2half(oacc[i][e]);
}

// ---------------------------------------------------------------- combine hash rounds (f16 in/out)
__global__ __launch_bounds__(256) void k_combine(
    const __half* __restrict__ o, const float* __restrict__ lg, __half* __restrict__ att) {
  int m = blockIdx.x; int b = m >> 11, t = m & 2047;
  int head = threadIdx.x >> 5, d0 = (threadIdx.x & 31) * 2;
  int bh = b * 8 + head;
  const float* lgp = lg + (long)bh * 8 * T_LEN + t;
  float l[8], mx = -3.4e38f;
  #pragma unroll
  for (int hh = 0; hh < 8; ++hh) { l[hh] = lgp[(long)hh * T_LEN]; mx = fmaxf(mx, l[hh]); }
  float sm = 0.f;
  #pragma unroll
  for (int hh = 0; hh < 8; ++hh) { l[hh] = expf(l[hh] - mx); sm += l[hh]; }
  float inv = 1.f / sm;
  float a0 = 0.f, a1 = 0.f;
  #pragma unroll
  for (int hh = 0; hh < 8; ++hh) {
    const __half* op = o + (((long)bh * 8 + hh) * T_LEN + t) * 64 + d0;
    float w_ = l[hh] * inv;
    a0 += w_ * __half2float(op[0]); a1 += w_ * __half2float(op[1]);
  }
  unsigned int u = (unsigned int)__half_as_ushort(__float2half(a0)) |
                   ((unsigned int)__half_as_ushort(__float2half(a1)) << 16);
  *(unsigned int*)&att[(long)m * 512 + head * 64 + d0] = u;
}

// ---------------------------------------------------------------- host
extern "C" void kernel_launch(void* const* d_in, const int* in_sizes, int n_in,
                              void* d_out, int out_size, void* d_ws, size_t ws_size,
                              hipStream_t stream) {
  const float* spec   = (const float*)d_in[0];
  const float* conv_w = (const float*)d_in[1];
  const float* conv_b = (const float*)d_in[2];
  const float* pe_row = (const float*)d_in[3];
  const float* pe_col = (const float*)d_in[4];
  const float* lnA_g  = (const float*)d_in[5];
  const float* lnA_b  = (const float*)d_in[6];
  const float* wqk    = (const float*)d_in[7];
  const float* wv     = (const float*)d_in[8];
  const float* wo     = (const float*)d_in[9];
  const float* bo     = (const float*)d_in[10];
  const float* lnF_g  = (const float*)d_in[11];
  const float* lnF_b  = (const float*)d_in[12];
  const float* w1     = (const float*)d_in[13];
  const float* b1     = (const float*)d_in[14];
  const float* w2     = (const float*)d_in[15];
  const float* b2     = (const float*)d_in[16];
  const float* lin_w  = (const float*)d_in[17];
  const float* lin_b  = (const float*)d_in[18];
  const float* rot    = (const float*)d_in[19];

  float* ws = (float*)d_ws;
  const long TOKF = (long)NTOK * 512;            // 2,097,152
  float* x1   = ws;
  float* x2   = x1 + TOKF;
  float* qkb  = x2 + TOKF;
  float* lg   = qkb + TOKF;                       // 262144
  __half* o16 = (__half*)(lg + 262144);           // 16.78M halves
  int*   stx  = (int*)(o16 + (long)16 * 8 * T_LEN * 64);
  int*   buckets = stx + (long)16 * NHASH * T_LEN;
  float* base = (float*)(buckets + (long)16 * NHASH * T_LEN);
  __half* xnh1  = (__half*)base;                  // TOKF halves each
  __half* xnh2  = (__half*)(base + TOKF / 2);
  __half* att16 = (__half*)(base + 2 * (TOKF / 2));
  __half* vb16  = (__half*)(base + 3 * (TOKF / 2));
  __half* kn16  = (__half*)(base + 4 * (TOKF / 2));
  float* qnorm  = base + 5 * (TOKF / 2);          // 32768
  float* h1region = qnorm + 32768;                // 4.19M floats
  __half* h1h   = (__half*)h1region;
  __half* colh1 = (__half*)h1region;              // alias (conv first): 4096*704 halves
  __half* colh2 = colh1 + (long)4096 * 704;
  float* wreg   = h1region + (long)NTOK * 1024;
  __half* w1h   = (__half*)wreg;                  // 1,048,576 halves
  __half* w2h   = (__half*)(wreg + 524288);
  __half* wqh1  = (__half*)(wreg + 2 * 524288);
  __half* wqh2  = (__half*)(wreg + 2 * 524288 + 131072);
  __half* wvh   = (__half*)(wreg + 2 * 524288 + 2 * 131072);
  __half* woh   = (__half*)(wreg + 2 * 524288 + 3 * 131072);
  __half* linh1 = (__half*)(wreg + 2 * 524288 + 4 * 131072);
  __half* linh2 = (__half*)(wreg + 2 * 524288 + 4 * 131072 + 32768);
  __half* cwh1  = w1h;                            // alias (conv first): 512*704 halves
  __half* cwh2  = w2h;

  // conv frontend: split-f16 MFMA GEMM (f32-grade)
  k_im2col2<<<NTOK, 256, 0, stream>>>(spec, colh1, colh2);
  k_wconv2<<<512, 256, 0, stream>>>(conv_w, cwh1, cwh2);
  k_mgemm2<0,1,1,0><<<512, 256, 0, stream>>>(
      (const ushort*)colh1, (const ushort*)colh2, (const ushort*)cwh1, (const ushort*)cwh2,
      conv_b, x1, NTOK, 512, 704, 8, 512);
  k_pe<<<NTOK, 256, 0, stream>>>(pe_row, pe_col, x1, x2);

  for (int l = 0; l < 8; ++l) {
    const long W2 = (long)l * 512 * 512;
    k_ln<1><<<NTOK, 256, 0, stream>>>(x2, lnA_g + l * 512, lnA_b + l * 512, xnh1, xnh2);
    // qk projection: split-f16 MFMA (f32-grade, feeds hashing)
    k_tcvt2<<<dim3(16, 16), 256, 0, stream>>>(wqk + W2, wqh1, wqh2, 512, 512);
    k_mgemm2<1,0,0,0><<<512, 256, 0, stream>>>(
        (const ushort*)xnh1, (const ushort*)xnh2, (const ushort*)wqh1, (const ushort*)wqh2,
        nullptr, qkb, NTOK, 512, 512, 8, 512);
    // v projection via f16 MFMA, scattered per head
    k_tcvt<<<dim3(16, 16), 256, 0, stream>>>(wv + W2, wvh, 512, 512);
    k_mgemm<1,0,0,0><<<512, 256, 0, stream>>>(
        (const ushort*)xnh1, (const ushort*)wvh, nullptr, vb16, nullptr, NTOK, 512, 512, 8);
    k_qprep<<<8192, 256, 0, stream>>>(qkb, kn16, qnorm);
    k_hash<<<1024, 256, 0, stream>>>(qkb, rot + (long)l * 8192, buckets);
    k_sort<<<128, 256, 0, stream>>>(buckets, stx);
    k_attn_mfma<<<4096, 256, 0, stream>>>((const ushort*)kn16, qnorm, (const ushort*)vb16,
                                          stx, o16, lg);
    k_combine<<<NTOK, 256, 0, stream>>>(o16, lg, att16);
    // wo projection via f16 MFMA, residual into x1
    k_tcvt<<<dim3(16, 16), 256, 0, stream>>>(wo + W2, woh, 512, 512);
    k_mgemm<0,1,0,1><<<512, 256, 0, stream>>>(
        (const ushort*)att16, (const ushort*)woh, bo + l * 512, nullptr, x1, NTOK, 512, 512, 8);
    // FFN via f16 MFMA
    k_ln<0><<<NTOK, 256, 0, stream>>>(x1, lnF_g + l * 512, lnF_b + l * 512, xnh1, nullptr);
    k_tcvt<<<dim3(64, 16), 256, 0, stream>>>(w1 + (long)l * 512 * 2048, w1h, 512, 2048);
    k_mgemm<0,1,1,0><<<2048, 256, 0, stream>>>(
        (const ushort*)xnh1, (const ushort*)w1h, b1 + (long)l * 2048, h1h, nullptr, NTOK, 2048, 512, 32);
    k_tcvt<<<dim3(16, 64), 256, 0, stream>>>(w2 + (long)l * 2048 * 512, w2h, 2048, 512);
    k_mgemm<0,1,0,1><<<512, 256, 0, stream>>>(
        (const ushort*)h1h, (const ushort*)w2h, b2 + (long)l * 512, nullptr, x2, NTOK, 512, 2048, 8);
  }
  // final linear: split-f16 (N padded to 128, real 88)
  k_halfcvt<<<NTOK, 256, 0, stream>>>(x1, x2, xnh1, xnh2);
  k_tcvt2<<<dim3(4, 16), 256, 0, stream>>>(lin_w, linh1, linh2, 512, 88);
  k_mgemm2<0,1,0,1><<<128, 256, 0, stream>>>(
      (const ushort*)xnh1, (const ushort*)xnh2, (const ushort*)linh1, (const ushort*)linh2,
      lin_b, (float*)d_out, NTOK, 128, 512, 2, 88);
}

// Round 8
// 1867.293 us; speedup vs baseline: 1.0372x; 1.0372x over previous
//
#include <hip/hip_runtime.h>
#include <hip/hip_fp16.h>
#include <cstdint>

#define T_LEN 2048
#define NTOK  4096      // B*T
#define NHASH 8
#define SELF_VAL -5e4f
#define SPLIT_S 2048.f
#define SPLIT_IS (1.f/2048.f)

typedef __attribute__((ext_vector_type(8))) short short8v;
typedef __attribute__((ext_vector_type(8))) _Float16 half8v;
typedef __attribute__((ext_vector_type(4))) float f32x4;
typedef __attribute__((ext_vector_type(4))) unsigned short ushort4v;

__device__ inline void split16(float v, __half& h1, __half& h2) {
  h1 = __float2half(v);
  h2 = __float2half((v - __half2float(h1)) * SPLIT_S);
}

// ---------------------------------------------------------------- im2col split-f16 (conv k=3 pad=1), K padded to 704
__global__ __launch_bounds__(256) void k_im2col2(
    const float* __restrict__ spec, __half* __restrict__ c1, __half* __restrict__ c2) {
  int m = blockIdx.x; int b = m >> 11, t = m & 2047;
  for (int c = threadIdx.x; c < 704; c += 256) {
    float v = 0.f;
    if (c < 687) {
      int k = (c >= 458) ? 2 : (c >= 229 ? 1 : 0);
      int i = c - k * 229;
      int tt = t + k - 1;
      if (tt >= 0 && tt < T_LEN) v = spec[((long)b * T_LEN + tt) * 229 + i];
    }
    __half h1, h2; split16(v, h1, h2);
    c1[(long)m * 704 + c] = h1; c2[(long)m * 704 + c] = h2;
  }
}

// conv weight split, Bt layout [o][c=k*229+i], c padded to 704
__global__ __launch_bounds__(256) void k_wconv2(
    const float* __restrict__ w, __half* __restrict__ d1, __half* __restrict__ d2) {
  int o = blockIdx.x;
  for (int c = threadIdx.x; c < 704; c += 256) {
    float v = 0.f;
    if (c < 687) {
      int k = (c >= 458) ? 2 : (c >= 229 ? 1 : 0);
      int i = c - k * 229;
      v = w[((long)o * 229 + i) * 3 + k];
    }
    __half h1, h2; split16(v, h1, h2);
    d1[(long)o * 704 + c] = h1; d2[(long)o * 704 + c] = h2;
  }
}

__global__ __launch_bounds__(256) void k_pe(
    const float* __restrict__ pe_row, const float* __restrict__ pe_col,
    float* __restrict__ x1, float* __restrict__ x2) {
  int m = blockIdx.x, t = m & 2047;
  for (int o = threadIdx.x; o < 512; o += 256) {
    long idx = (long)m * 512 + o;
    float v = x1[idx] + ((o < 256) ? pe_row[(t >> 6) * 256 + o]
                                   : pe_col[(t & 63) * 256 + (o - 256)]);
    x1[idx] = v; x2[idx] = v;
  }
}

// zero 8MB qkb: 2048 blocks x 256 thr x float4
__global__ __launch_bounds__(256) void k_zero(float* __restrict__ p) {
  long i = ((long)blockIdx.x * 256 + threadIdx.x) * 4;
  *(float4*)(p + i) = make_float4(0.f, 0.f, 0.f, 0.f);
}

// ---------------------------------------------------------------- layernorm; SPLIT: also emit scaled f16 correction
template<int SPLIT>
__global__ __launch_bounds__(256) void k_ln(
    const float* __restrict__ x, const float* __restrict__ g,
    const float* __restrict__ bb, __half* __restrict__ o1, __half* __restrict__ o2) {
  int row = blockIdx.x, tid = threadIdx.x;
  const float* xr = x + (long)row * 512;
  float v0 = xr[tid], v1 = xr[tid + 256];
  float s1 = v0 + v1, s2 = v0 * v0 + v1 * v1;
  #pragma unroll
  for (int off = 1; off < 64; off <<= 1) { s1 += __shfl_xor(s1, off); s2 += __shfl_xor(s2, off); }
  __shared__ float r1[4], r2[4];
  int w = tid >> 6, lane = tid & 63;
  if (lane == 0) { r1[w] = s1; r2[w] = s2; }
  __syncthreads();
  float S1 = r1[0] + r1[1] + r1[2] + r1[3];
  float S2 = r2[0] + r2[1] + r2[2] + r2[3];
  float mean = S1 * (1.f / 512.f);
  float var  = S2 * (1.f / 512.f) - mean * mean;
  float rstd = 1.f / sqrtf(var + 1e-5f);
  float a0 = (v0 - mean) * rstd * g[tid] + bb[tid];
  float a1 = (v1 - mean) * rstd * g[tid + 256] + bb[tid + 256];
  if (SPLIT) {
    __half h1, h2;
    split16(a0, h1, h2); o1[(long)row * 512 + tid] = h1; o2[(long)row * 512 + tid] = h2;
    split16(a1, h1, h2); o1[(long)row * 512 + tid + 256] = h1; o2[(long)row * 512 + tid + 256] = h2;
  } else {
    o1[(long)row * 512 + tid]       = __float2half(a0);
    o1[(long)row * 512 + tid + 256] = __float2half(a1);
  }
}

// 0.5*(x1+x2) -> split f16
__global__ __launch_bounds__(256) void k_halfcvt(
    const float* __restrict__ x1, const float* __restrict__ x2,
    __half* __restrict__ a1, __half* __restrict__ a2) {
  long idx = (long)blockIdx.x * 512 + threadIdx.x;
  #pragma unroll
  for (int rep = 0; rep < 2; ++rep, idx += 256) {
    float v = 0.5f * (x1[idx] + x2[idx]);
    __half h1, h2; split16(v, h1, h2);
    a1[idx] = h1; a2[idx] = h2;
  }
}

// ---------------------------------------------------------------- split-f16 MFMA GEMM (f32-grade): conv/lin (no split-K)
template<int MAP, int BIAS, int RELU, int NG>
__global__ __launch_bounds__(256) void k_mgemm2(
    const ushort* __restrict__ A1, const ushort* __restrict__ A2,
    const ushort* __restrict__ B1, const ushort* __restrict__ B2,
    const float* __restrict__ bias, float* __restrict__ C,
    int M, int N, int K, int ncol, int Nreal) {
  __shared__ ushort As1[64 * 40], As2[64 * 40], Bs1[64 * 40], Bs2[64 * 40];
  int tid = threadIdx.x;
  int nwg = gridDim.x, q8 = nwg >> 3, wg = blockIdx.x;
  int swz = (wg & 7) * q8 + (wg >> 3);
  int m0 = (swz / ncol) * 64, n0 = (swz % ncol) * 64;
  int wid = tid >> 6, lane = tid & 63;
  int wr = wid >> 1, wc = wid & 1;
  int r = lane & 15, kg = lane >> 4;
  int ar = tid >> 2, ac = tid & 3;
  f32x4 accM[2][2] = {}, accC[2][2] = {};
  for (int k0 = 0; k0 < K; k0 += 32) {
    __syncthreads();
    *(short8v*)&As1[ar * 40 + ac * 8] = *(const short8v*)(A1 + (long)(m0 + ar) * K + k0 + ac * 8);
    *(short8v*)&As2[ar * 40 + ac * 8] = *(const short8v*)(A2 + (long)(m0 + ar) * K + k0 + ac * 8);
    *(short8v*)&Bs1[ar * 40 + ac * 8] = *(const short8v*)(B1 + (long)(n0 + ar) * K + k0 + ac * 8);
    *(short8v*)&Bs2[ar * 40 + ac * 8] = *(const short8v*)(B2 + (long)(n0 + ar) * K + k0 + ac * 8);
    __syncthreads();
    half8v a1[2], a2[2], b1[2], b2[2];
    #pragma unroll
    for (int i = 0; i < 2; ++i) {
      a1[i] = *(const half8v*)&As1[(wr * 32 + i * 16 + r) * 40 + kg * 8];
      a2[i] = *(const half8v*)&As2[(wr * 32 + i * 16 + r) * 40 + kg * 8];
    }
    #pragma unroll
    for (int j = 0; j < 2; ++j) {
      b1[j] = *(const half8v*)&Bs1[(wc * 32 + j * 16 + r) * 40 + kg * 8];
      b2[j] = *(const half8v*)&Bs2[(wc * 32 + j * 16 + r) * 40 + kg * 8];
    }
    #pragma unroll
    for (int i = 0; i < 2; ++i)
      #pragma unroll
      for (int j = 0; j < 2; ++j) {
        accM[i][j] = __builtin_amdgcn_mfma_f32_16x16x32_f16(a1[i], b1[j], accM[i][j], 0, 0, 0);
        accC[i][j] = __builtin_amdgcn_mfma_f32_16x16x32_f16(a1[i], b2[j], accC[i][j], 0, 0, 0);
        accC[i][j] = __builtin_amdgcn_mfma_f32_16x16x32_f16(a2[i], b1[j], accC[i][j], 0, 0, 0);
      }
  }
  #pragma unroll
  for (int i = 0; i < 2; ++i) {
    int mb = m0 + wr * 32 + i * 16 + kg * 4;
    #pragma unroll
    for (int j = 0; j < 2; ++j) {
      int n = n0 + wc * 32 + j * 16 + r;
      if (NG && n >= Nreal) continue;
      float bv = BIAS ? bias[n] : 0.f;
      #pragma unroll
      for (int q = 0; q < 4; ++q) {
        float v = accM[i][j][q] + accC[i][j][q] * SPLIT_IS + bv;
        if (RELU) v = fmaxf(v, 0.f);
        long idx;
        if (MAP == 1) {
          int m = mb + q;
          int b = m >> 11, t = m & 2047, hh = n >> 6, dd = n & 63;
          idx = (((long)(b * 8 + hh)) * T_LEN + t) * 64 + dd;
        } else {
          idx = (long)(mb + q) * Nreal + n;
        }
        C[idx] = v;
      }
    }
  }
}

// ---------------------------------------------------------------- split-f16 MFMA GEMM, split-K + atomicAdd (qk)
// MAP1 scatter; C must be zero-initialized. nbase % 8 == 0.
__global__ __launch_bounds__(256) void k_mgemm2_sk(
    const ushort* __restrict__ A1, const ushort* __restrict__ A2,
    const ushort* __restrict__ B1, const ushort* __restrict__ B2,
    float* __restrict__ C, int M, int N, int K, int ncol, int nbase, int Kc) {
  __shared__ ushort As1[64 * 40], As2[64 * 40], Bs1[64 * 40], Bs2[64 * 40];
  int tid = threadIdx.x;
  int s = blockIdx.x / nbase, wg = blockIdx.x % nbase;
  int q8 = nbase >> 3;
  int swz = (wg & 7) * q8 + (wg >> 3);
  int m0 = (swz / ncol) * 64, n0 = (swz % ncol) * 64;
  int wid = tid >> 6, lane = tid & 63;
  int wr = wid >> 1, wc = wid & 1;
  int r = lane & 15, kg = lane >> 4;
  int ar = tid >> 2, ac = tid & 3;
  f32x4 accM[2][2] = {}, accC[2][2] = {};
  int kend = s * Kc + Kc;
  for (int k0 = s * Kc; k0 < kend; k0 += 32) {
    __syncthreads();
    *(short8v*)&As1[ar * 40 + ac * 8] = *(const short8v*)(A1 + (long)(m0 + ar) * K + k0 + ac * 8);
    *(short8v*)&As2[ar * 40 + ac * 8] = *(const short8v*)(A2 + (long)(m0 + ar) * K + k0 + ac * 8);
    *(short8v*)&Bs1[ar * 40 + ac * 8] = *(const short8v*)(B1 + (long)(n0 + ar) * K + k0 + ac * 8);
    *(short8v*)&Bs2[ar * 40 + ac * 8] = *(const short8v*)(B2 + (long)(n0 + ar) * K + k0 + ac * 8);
    __syncthreads();
    half8v a1[2], a2[2], b1[2], b2[2];
    #pragma unroll
    for (int i = 0; i < 2; ++i) {
      a1[i] = *(const half8v*)&As1[(wr * 32 + i * 16 + r) * 40 + kg * 8];
      a2[i] = *(const half8v*)&As2[(wr * 32 + i * 16 + r) * 40 + kg * 8];
    }
    #pragma unroll
    for (int j = 0; j < 2; ++j) {
      b1[j] = *(const half8v*)&Bs1[(wc * 32 + j * 16 + r) * 40 + kg * 8];
      b2[j] = *(const half8v*)&Bs2[(wc * 32 + j * 16 + r) * 40 + kg * 8];
    }
    #pragma unroll
    for (int i = 0; i < 2; ++i)
      #pragma unroll
      for (int j = 0; j < 2; ++j) {
        accM[i][j] = __builtin_amdgcn_mfma_f32_16x16x32_f16(a1[i], b1[j], accM[i][j], 0, 0, 0);
        accC[i][j] = __builtin_amdgcn_mfma_f32_16x16x32_f16(a1[i], b2[j], accC[i][j], 0, 0, 0);
        accC[i][j] = __builtin_amdgcn_mfma_f32_16x16x32_f16(a2[i], b1[j], accC[i][j], 0, 0, 0);
      }
  }
  #pragma unroll
  for (int i = 0; i < 2; ++i) {
    int mb = m0 + wr * 32 + i * 16 + kg * 4;
    #pragma unroll
    for (int j = 0; j < 2; ++j) {
      int n = n0 + wc * 32 + j * 16 + r;
      #pragma unroll
      for (int q = 0; q < 4; ++q) {
        float v = accM[i][j][q] + accC[i][j][q] * SPLIT_IS;
        int m = mb + q;
        int b = m >> 11, t = m & 2047, hh = n >> 6, dd = n & 63;
        long idx = (((long)(b * 8 + hh)) * T_LEN + t) * 64 + dd;
        atomicAdd(&C[idx], v);
      }
    }
  }
}

// ---------------------------------------------------------------- f16 MFMA GEMM (v/FFN1), 64x64 tile, BK=32
template<int MAP, int BIAS, int GELU, int RES>
__global__ __launch_bounds__(256) void k_mgemm(
    const ushort* __restrict__ A, const ushort* __restrict__ Bt,
    const float* __restrict__ bias, __half* __restrict__ Ch,
    float* __restrict__ Cf, int M, int N, int K, int ncol) {
  __shared__ ushort As[64 * 40];
  __shared__ ushort Bs[64 * 40];
  int tid = threadIdx.x;
  int nwg = gridDim.x, q8 = nwg >> 3, wg = blockIdx.x;
  int swz = (wg & 7) * q8 + (wg >> 3);
  int m0 = (swz / ncol) * 64, n0 = (swz % ncol) * 64;
  int wid = tid >> 6, lane = tid & 63;
  int wr = wid >> 1, wc = wid & 1;
  int r = lane & 15, kg = lane >> 4;
  int ar = tid >> 2, ac = tid & 3;
  f32x4 acc[2][2] = {};
  for (int k0 = 0; k0 < K; k0 += 32) {
    __syncthreads();
    *(short8v*)&As[ar * 40 + ac * 8] =
        *(const short8v*)(A + (long)(m0 + ar) * K + k0 + ac * 8);
    *(short8v*)&Bs[ar * 40 + ac * 8] =
        *(const short8v*)(Bt + (long)(n0 + ar) * K + k0 + ac * 8);
    __syncthreads();
    half8v af[2], bf[2];
    #pragma unroll
    for (int i = 0; i < 2; ++i)
      af[i] = *(const half8v*)&As[(wr * 32 + i * 16 + r) * 40 + kg * 8];
    #pragma unroll
    for (int j = 0; j < 2; ++j)
      bf[j] = *(const half8v*)&Bs[(wc * 32 + j * 16 + r) * 40 + kg * 8];
    #pragma unroll
    for (int i = 0; i < 2; ++i)
      #pragma unroll
      for (int j = 0; j < 2; ++j)
        acc[i][j] = __builtin_amdgcn_mfma_f32_16x16x32_f16(af[i], bf[j], acc[i][j], 0, 0, 0);
  }
  #pragma unroll
  for (int i = 0; i < 2; ++i) {
    int mb = m0 + wr * 32 + i * 16 + kg * 4;
    #pragma unroll
    for (int j = 0; j < 2; ++j) {
      int n = n0 + wc * 32 + j * 16 + r;
      float bv = BIAS ? bias[n] : 0.f;
      #pragma unroll
      for (int q = 0; q < 4; ++q) {
        float v = acc[i][j][q] + bv;
        if (GELU) v = 0.5f * v * (1.f + erff(v * 0.70710678118654752f));
        long idx;
        if (MAP == 1) {
          int m = mb + q;
          int b = m >> 11, t = m & 2047, hh = n >> 6, dd = n & 63;
          idx = (((long)(b * 8 + hh)) * T_LEN + t) * 64 + dd;
        } else {
          idx = (long)(mb + q) * N + n;
        }
        if (RES) Cf[idx] += v;
        else Ch[idx] = __float2half(v);
      }
    }
  }
}

// ---------------------------------------------------------------- f16 MFMA GEMM, split-K + atomicAdd (wo/FFN2)
// bias added by s==0 only. nbase % 8 == 0.
template<int BIAS>
__global__ __launch_bounds__(256) void k_mgemm_sk(
    const ushort* __restrict__ A, const ushort* __restrict__ Bt,
    const float* __restrict__ bias, float* __restrict__ Cf,
    int M, int N, int K, int ncol, int nbase, int Kc) {
  __shared__ ushort As[64 * 40];
  __shared__ ushort Bs[64 * 40];
  int tid = threadIdx.x;
  int s = blockIdx.x / nbase, wg = blockIdx.x % nbase;
  int q8 = nbase >> 3;
  int swz = (wg & 7) * q8 + (wg >> 3);
  int m0 = (swz / ncol) * 64, n0 = (swz % ncol) * 64;
  int wid = tid >> 6, lane = tid & 63;
  int wr = wid >> 1, wc = wid & 1;
  int r = lane & 15, kg = lane >> 4;
  int ar = tid >> 2, ac = tid & 3;
  f32x4 acc[2][2] = {};
  int kend = s * Kc + Kc;
  for (int k0 = s * Kc; k0 < kend; k0 += 32) {
    __syncthreads();
    *(short8v*)&As[ar * 40 + ac * 8] =
        *(const short8v*)(A + (long)(m0 + ar) * K + k0 + ac * 8);
    *(short8v*)&Bs[ar * 40 + ac * 8] =
        *(const short8v*)(Bt + (long)(n0 + ar) * K + k0 + ac * 8);
    __syncthreads();
    half8v af[2], bf[2];
    #pragma unroll
    for (int i = 0; i < 2; ++i)
      af[i] = *(const half8v*)&As[(wr * 32 + i * 16 + r) * 40 + kg * 8];
    #pragma unroll
    for (int j = 0; j < 2; ++j)
      bf[j] = *(const half8v*)&Bs[(wc * 32 + j * 16 + r) * 40 + kg * 8];
    #pragma unroll
    for (int i = 0; i < 2; ++i)
      #pragma unroll
      for (int j = 0; j < 2; ++j)
        acc[i][j] = __builtin_amdgcn_mfma_f32_16x16x32_f16(af[i], bf[j], acc[i][j], 0, 0, 0);
  }
  #pragma unroll
  for (int i = 0; i < 2; ++i) {
    int mb = m0 + wr * 32 + i * 16 + kg * 4;
    #pragma unroll
    for (int j = 0; j < 2; ++j) {
      int n = n0 + wc * 32 + j * 16 + r;
      float bv = (BIAS && s == 0) ? bias[n] : 0.f;
      #pragma unroll
      for (int q = 0; q < 4; ++q)
        atomicAdd(&Cf[(long)(mb + q) * N + n], acc[i][j][q] + bv);
    }
  }
}

// tiled transpose + f32->f16, z = layer: dst[c][r] = h(src[r][c])
__global__ __launch_bounds__(256) void k_tcvt_z(
    const float* __restrict__ src0, __half* __restrict__ dst0, int R, int C) {
  __shared__ float tile[32][33];
  long lo = (long)blockIdx.z * R * C;
  const float* src = src0 + lo;
  __half* dst = dst0 + lo;
  int c0 = blockIdx.x * 32, r0 = blockIdx.y * 32;
  int tx = threadIdx.x & 31, ty = threadIdx.x >> 5;
  #pragma unroll
  for (int i = 0; i < 4; ++i)
    tile[ty + i * 8][tx] = src[(long)(r0 + ty + i * 8) * C + c0 + tx];
  __syncthreads();
  #pragma unroll
  for (int i = 0; i < 4; ++i)
    dst[(long)(c0 + ty + i * 8) * R + r0 + tx] = __float2half(tile[tx][ty + i * 8]);
}

// tiled transpose + split pair, z = layer
__global__ __launch_bounds__(256) void k_tcvt2_z(
    const float* __restrict__ src0, __half* __restrict__ d10, __half* __restrict__ d20,
    int R, int C) {
  __shared__ float tile[32][33];
  long lo = (long)blockIdx.z * R * C;
  const float* src = src0 + lo;
  __half* d1 = d10 + lo; __half* d2 = d20 + lo;
  int c0 = blockIdx.x * 32, r0 = blockIdx.y * 32;
  int tx = threadIdx.x & 31, ty = threadIdx.x >> 5;
  #pragma unroll
  for (int i = 0; i < 4; ++i)
    tile[ty + i * 8][tx] = src[(long)(r0 + ty + i * 8) * C + c0 + tx];
  __syncthreads();
  #pragma unroll
  for (int i = 0; i < 4; ++i) {
    float v = tile[tx][ty + i * 8];
    __half h1, h2; split16(v, h1, h2);
    long o = (long)(c0 + ty + i * 8) * R + r0 + tx;
    d1[o] = h1; d2[o] = h2;
  }
}

// tiled transpose + split pair, col-padded (final lin weight)
__global__ __launch_bounds__(256) void k_tcvt2(
    const float* __restrict__ src, __half* __restrict__ d1, __half* __restrict__ d2,
    int R, int C) {
  __shared__ float tile[32][33];
  int c0 = blockIdx.x * 32, r0 = blockIdx.y * 32;
  int tx = threadIdx.x & 31, ty = threadIdx.x >> 5;
  #pragma unroll
  for (int i = 0; i < 4; ++i) {
    int c = c0 + tx;
    tile[ty + i * 8][tx] = (c < C) ? src[(long)(r0 + ty + i * 8) * C + c] : 0.f;
  }
  __syncthreads();
  #pragma unroll
  for (int i = 0; i < 4; ++i) {
    float v = tile[tx][ty + i * 8];
    __half h1, h2; split16(v, h1, h2);
    long o = (long)(c0 + ty + i * 8) * R + r0 + tx;
    d1[o] = h1; d2[o] = h2;
  }
}

// ---------------------------------------------------------------- qk prep: normalized f16 K + f32 row norm
__global__ __launch_bounds__(256) void k_qprep(
    const float* __restrict__ qk, __half* __restrict__ kn, float* __restrict__ qnorm) {
  int row = blockIdx.x * 4 + (threadIdx.x >> 6);
  int d = threadIdx.x & 63;
  float v = qk[(long)row * 64 + d];
  float s2 = v * v;
  #pragma unroll
  for (int off = 1; off < 64; off <<= 1) s2 += __shfl_xor(s2, off);
  float nrm = fmaxf(sqrtf(s2), 1e-12f);
  kn[(long)row * 64 + d] = __float2half(v / nrm);
  if (d == 0) qnorm[row] = nrm;
}

// ---------------------------------------------------------------- LSH hashing (f32)
__global__ __launch_bounds__(256) void k_hash(
    const float* __restrict__ qk, const float* __restrict__ rot,
    int* __restrict__ buckets) {
  int bhid = blockIdx.x >> 6; int t0 = (blockIdx.x & 63) * 32;
  __shared__ float qrow[32][64];
  __shared__ float rl[64][8][20];
  for (int idx = threadIdx.x; idx < 32 * 64; idx += 256) {
    int tok = idx >> 6, f = idx & 63;
    qrow[tok][f] = qk[((long)bhid * T_LEN + t0 + tok) * 64 + f];
  }
  for (int idx = threadIdx.x; idx < 64 * 128; idx += 256) {
    int f = idx >> 7, rem = idx & 127, hh = rem >> 4, ii = rem & 15;
    rl[f][hh][ii] = rot[idx];
  }
  __syncthreads();
  int tok = threadIdx.x >> 3, h = threadIdx.x & 7;
  float acc[16] = {};
  for (int f = 0; f < 64; ++f) {
    float qv = qrow[tok][f];
    #pragma unroll
    for (int i = 0; i < 16; ++i) acc[i] += qv * rl[f][h][i];
  }
  float best = acc[0]; int bi = 0;
  #pragma unroll
  for (int i = 1; i < 16; ++i) if (acc[i] > best) { best = acc[i]; bi = i; }
  #pragma unroll
  for (int i = 0; i < 16; ++i) if (-acc[i] > best) { best = -acc[i]; bi = 16 + i; }
  buckets[((long)bhid * 8 + h) * T_LEN + t0 + tok] = bi;
}

// ---------------------------------------------------------------- stable counting sort
__global__ __launch_bounds__(256) void k_sort(
    const int* __restrict__ buckets, int* __restrict__ st) {
  int bh = blockIdx.x >> 3, h = blockIdx.x & 7;
  const int* bk = buckets + ((long)bh * 8 + h) * T_LEN;
  __shared__ unsigned char lb[2048];
  __shared__ int hist[32], cnt[32];
  __shared__ int whist[4][32];
  if (threadIdx.x < 32) hist[threadIdx.x] = 0;
  __syncthreads();
  for (int p = threadIdx.x; p < 2048; p += 256) {
    int v = bk[p]; lb[p] = (unsigned char)v; atomicAdd(&hist[v], 1);
  }
  __syncthreads();
  if (threadIdx.x == 0) {
    int run = 0;
    for (int i = 0; i < 32; ++i) { cnt[i] = run; run += hist[i]; }
  }
  __syncthreads();
  int lane = threadIdx.x & 63, w = threadIdx.x >> 6;
  unsigned long long mlt = (1ull << lane) - 1ull;
  int* outp = st + (long)bh * (NHASH * T_LEN) + h * T_LEN;
  for (int tile = 0; tile < 8; ++tile) {
    int p = tile * 256 + threadIdx.x;
    int myb = lb[p];
    int wrank = 0;
    for (int bv = 0; bv < 32; ++bv) {
      unsigned long long mm = __ballot(myb == bv);
      if (myb == bv) wrank = __popcll(mm & mlt);
      if (lane == bv) whist[w][bv] = __popcll(mm);
    }
    __syncthreads();
    int off = cnt[myb];
    for (int w2 = 0; w2 < w; ++w2) off += whist[w2][myb];
    outp[off + wrank] = p;
    __syncthreads();
    if (threadIdx.x < 32)
      cnt[threadIdx.x] += whist[0][threadIdx.x] + whist[1][threadIdx.x] +
                          whist[2][threadIdx.x] + whist[3][threadIdx.x];
    __syncthreads();
  }
}

// ---------------------------------------------------------------- MFMA chunked attention (o out f16)
// Ps aliases Kb (dead after QK^T) -> LDS ~36.6KB -> 4 blocks/CU.
__global__ __launch_bounds__(256) void k_attn_mfma(
    const ushort* __restrict__ kn, const float* __restrict__ qnorm,
    const ushort* __restrict__ vv, const int* __restrict__ st,
    __half* __restrict__ o, float* __restrict__ lg) {
  __shared__ ushort KbPs[128 * 72];   // Kb [kv][72] during QK; Ps [q][136] during PV
  __shared__ ushort Vt[64 * 136];
  __shared__ int   kpos[128];
  __shared__ float qn[64];
  int bh = blockIdx.x >> 8, c = blockIdx.x & 255;
  int h = c >> 5, cp = (c + 255) & 255;
  int tid = threadIdx.x, lane = tid & 63, w = tid >> 6;
  int r16 = lane & 15, kg = lane >> 4;
  const int* stb = st + (long)bh * (NHASH * T_LEN);
  if (tid < 128) kpos[tid] = stb[((tid < 64) ? c : cp) * 64 + (tid & 63)];
  __syncthreads();
  if (tid < 64) qn[tid] = qnorm[bh * T_LEN + kpos[tid]];
  const ushort* knb = kn + (long)bh * T_LEN * 64;
  const ushort* vvb = vv + (long)bh * T_LEN * 64;
  for (int idx = tid; idx < 1024; idx += 256) {
    int rr = idx >> 3, p = idx & 7;
    *(short8v*)&KbPs[rr * 72 + p * 8] = *(const short8v*)(knb + (long)kpos[rr] * 64 + p * 8);
  }
  {
    int rr = (tid & 63) * 2;
    ushort a[16], b[16];
    *(short8v*)&a[0] = *(const short8v*)(vvb + (long)kpos[rr] * 64 + w * 16);
    *(short8v*)&a[8] = *(const short8v*)(vvb + (long)kpos[rr] * 64 + w * 16 + 8);
    *(short8v*)&b[0] = *(const short8v*)(vvb + (long)kpos[rr + 1] * 64 + w * 16);
    *(short8v*)&b[8] = *(const short8v*)(vvb + (long)kpos[rr + 1] * 64 + w * 16 + 8);
    #pragma unroll
    for (int i = 0; i < 16; ++i) {
      int d = w * 16 + i;
      *(unsigned int*)&Vt[d * 136 + rr] = (unsigned int)a[i] | ((unsigned int)b[i] << 16);
    }
  }
  __syncthreads();
  f32x4 sacc[8] = {};
  #pragma unroll
  for (int ks = 0; ks < 2; ++ks) {
    half8v bfq = *(const half8v*)&KbPs[(w * 16 + r16) * 72 + ks * 32 + kg * 8];
    #pragma unroll
    for (int i = 0; i < 8; ++i) {
      half8v af = *(const half8v*)&KbPs[(i * 16 + r16) * 72 + ks * 32 + kg * 8];
      sacc[i] = __builtin_amdgcn_mfma_f32_16x16x32_f16(af, bfq, sacc[i], 0, 0, 0);
    }
  }
  __syncthreads();   // Kb now dead; safe to overwrite with Ps
  int q = w * 16 + r16;
  int qposv = kpos[q];
  float sc = 0.125f * qn[q];
  float vals[8][4];
  float mx = -3.4e38f;
  #pragma unroll
  for (int f = 0; f < 8; ++f)
    #pragma unroll
    for (int e = 0; e < 4; ++e) {
      int kv = f * 16 + kg * 4 + e;
      float v = sacc[f][e] * sc;
      if (kpos[kv] == qposv) v = SELF_VAL;
      vals[f][e] = v;
      mx = fmaxf(mx, v);
    }
  mx = fmaxf(mx, __shfl_xor(mx, 16));
  mx = fmaxf(mx, __shfl_xor(mx, 32));
  float sm = 0.f;
  #pragma unroll
  for (int f = 0; f < 8; ++f)
    #pragma unroll
    for (int e = 0; e < 4; ++e) { vals[f][e] = __expf(vals[f][e] - mx); sm += vals[f][e]; }
  sm += __shfl_xor(sm, 16);
  sm += __shfl_xor(sm, 32);
  float inv = 1.f / sm;
  #pragma unroll
  for (int f = 0; f < 8; ++f) {
    ushort4v pw;
    #pragma unroll
    for (int e = 0; e < 4; ++e) pw[e] = __half_as_ushort(__float2half(vals[f][e] * inv));
    *(ushort4v*)&KbPs[q * 136 + f * 16 + kg * 4] = pw;
  }
  if (kg == 0) lg[((long)bh * 8 + h) * T_LEN + qposv] = mx + logf(sm);
  __syncthreads();
  f32x4 oacc[4] = {};
  #pragma unroll
  for (int ks = 0; ks < 4; ++ks) {
    half8v vf = *(const half8v*)&Vt[(w * 16 + r16) * 136 + ks * 32 + kg * 8];
    #pragma unroll
    for (int i = 0; i < 4; ++i) {
      half8v pf = *(const half8v*)&KbPs[(i * 16 + r16) * 136 + ks * 32 + kg * 8];
      oacc[i] = __builtin_amdgcn_mfma_f32_16x16x32_f16(pf, vf, oacc[i], 0, 0, 0);
    }
  }
  long ob = ((long)bh * 8 + h) * T_LEN;
  int d = w * 16 + r16;
  #pragma unroll
  for (int i = 0; i < 4; ++i)
    #pragma unroll
    for (int e = 0; e < 4; ++e)
      o[(ob + kpos[i * 16 + kg * 4 + e]) * 64 + d] = __float2half(oacc[i][e]);
}

// ---------------------------------------------------------------- combine hash rounds (f16 in/out)
__global__ __launch_bounds__(256) void k_combine(
    const __half* __restrict__ o, const float* __restrict__ lg, __half* __restrict__ att) {
  int m = blockIdx.x; int b = m >> 11, t = m & 2047;
  int head = threadIdx.x >> 5, d0 = (threadIdx.x & 31) * 2;
  int bh = b * 8 + head;
  const float* lgp = lg + (long)bh * 8 * T_LEN + t;
  float l[8], mx = -3.4e38f;
  #pragma unroll
  for (int hh = 0; hh < 8; ++hh) { l[hh] = lgp[(long)hh * T_LEN]; mx = fmaxf(mx, l[hh]); }
  float sm = 0.f;
  #pragma unroll
  for (int hh = 0; hh < 8; ++hh) { l[hh] = expf(l[hh] - mx); sm += l[hh]; }
  float inv = 1.f / sm;
  float a0 = 0.f, a1 = 0.f;
  #pragma unroll
  for (int hh = 0; hh < 8; ++hh) {
    const __half* op = o + (((long)bh * 8 + hh) * T_LEN + t) * 64 + d0;
    float w_ = l[hh] * inv;
    a0 += w_ * __half2float(op[0]); a1 += w_ * __half2float(op[1]);
  }
  unsigned int u = (unsigned int)__half_as_ushort(__float2half(a0)) |
                   ((unsigned int)__half_as_ushort(__float2half(a1)) << 16);
  *(unsigned int*)&att[(long)m * 512 + head * 64 + d0] = u;
}

// ---------------------------------------------------------------- host
extern "C" void kernel_launch(void* const* d_in, const int* in_sizes, int n_in,
                              void* d_out, int out_size, void* d_ws, size_t ws_size,
                              hipStream_t stream) {
  const float* spec   = (const float*)d_in[0];
  const float* conv_w = (const float*)d_in[1];
  const float* conv_b = (const float*)d_in[2];
  const float* pe_row = (const float*)d_in[3];
  const float* pe_col = (const float*)d_in[4];
  const float* lnA_g  = (const float*)d_in[5];
  const float* lnA_b  = (const float*)d_in[6];
  const float* wqk    = (const float*)d_in[7];
  const float* wv     = (const float*)d_in[8];
  const float* wo     = (const float*)d_in[9];
  const float* bo     = (const float*)d_in[10];
  const float* lnF_g  = (const float*)d_in[11];
  const float* lnF_b  = (const float*)d_in[12];
  const float* w1     = (const float*)d_in[13];
  const float* b1     = (const float*)d_in[14];
  const float* w2     = (const float*)d_in[15];
  const float* b2     = (const float*)d_in[16];
  const float* lin_w  = (const float*)d_in[17];
  const float* lin_b  = (const float*)d_in[18];
  const float* rot    = (const float*)d_in[19];

  float* ws = (float*)d_ws;
  const long TOKF = (long)NTOK * 512;            // 2,097,152
  float* x1   = ws;
  float* x2   = x1 + TOKF;
  float* qkb  = x2 + TOKF;
  float* lg   = qkb + TOKF;                       // 262,144
  __half* o16 = (__half*)(lg + 262144);           // 16,777,216 halves
  int*   stx  = (int*)(o16 + (long)16777216);     // 262,144
  int*   buckets = stx + 262144;                  // 262,144
  float* base = (float*)(buckets + 262144);
  __half* xnh1  = (__half*)base;                  // TOKF halves each
  __half* xnh2  = (__half*)(base + TOKF / 2);
  __half* att16 = (__half*)(base + 2 * (TOKF / 2));
  __half* vb16  = (__half*)(base + 3 * (TOKF / 2));
  __half* kn16  = (__half*)(base + 4 * (TOKF / 2));
  float* qnorm  = base + 5 * (TOKF / 2);          // 32,768
  __half* h1h   = (__half*)(qnorm + 32768);       // 8,388,608 halves
  __half* colh1 = h1h;                            // alias (conv first): 2,883,584 h
  __half* colh2 = colh1 + (long)4096 * 704;       // 2,883,584 h (total < 8,388,608)
  float* wall   = (float*)(h1h + (long)8388608);
  __half* w1h   = (__half*)wall;                                  // 8 x 1,048,576 h
  __half* w2h   = (__half*)(wall + 4194304);                      // 8 x 1,048,576 h
  __half* wqh1  = (__half*)(wall + 2 * 4194304);                  // 8 x 262,144 h
  __half* wqh2  = (__half*)(wall + 2 * 4194304 + 1048576);
  __half* wvh   = (__half*)(wall + 2 * 4194304 + 2 * 1048576);
  __half* woh   = (__half*)(wall + 2 * 4194304 + 3 * 1048576);
  __half* cwh1  = (__half*)(wall + 2 * 4194304 + 4 * 1048576);    // 360,448 h
  __half* cwh2  = (__half*)(wall + 2 * 4194304 + 4 * 1048576 + 180224);
  __half* linh1 = (__half*)(wall + 2 * 4194304 + 4 * 1048576 + 2 * 180224);
  __half* linh2 = (__half*)(wall + 2 * 4194304 + 4 * 1048576 + 2 * 180224 + 32768);

  // ---- all weight conversions upfront (batched over layers) ----
  k_tcvt_z <<<dim3(64, 16, 8), 256, 0, stream>>>(w1,  w1h, 512, 2048);
  k_tcvt_z <<<dim3(16, 64, 8), 256, 0, stream>>>(w2,  w2h, 2048, 512);
  k_tcvt2_z<<<dim3(16, 16, 8), 256, 0, stream>>>(wqk, wqh1, wqh2, 512, 512);
  k_tcvt_z <<<dim3(16, 16, 8), 256, 0, stream>>>(wv,  wvh, 512, 512);
  k_tcvt_z <<<dim3(16, 16, 8), 256, 0, stream>>>(wo,  woh, 512, 512);
  k_wconv2 <<<512, 256, 0, stream>>>(conv_w, cwh1, cwh2);
  k_tcvt2  <<<dim3(4, 16), 256, 0, stream>>>(lin_w, linh1, linh2, 512, 88);

  // conv frontend: split-f16 MFMA GEMM (f32-grade)
  k_im2col2<<<NTOK, 256, 0, stream>>>(spec, colh1, colh2);
  k_mgemm2<0,1,1,0><<<512, 256, 0, stream>>>(
      (const ushort*)colh1, (const ushort*)colh2, (const ushort*)cwh1, (const ushort*)cwh2,
      conv_b, x1, NTOK, 512, 704, 8, 512);
  k_pe<<<NTOK, 256, 0, stream>>>(pe_row, pe_col, x1, x2);

  for (int l = 0; l < 8; ++l) {
    const long WQ = (long)l * 262144;
    k_ln<1><<<NTOK, 256, 0, stream>>>(x2, lnA_g + l * 512, lnA_b + l * 512, xnh1, xnh2);
    // qk projection: split-f16 MFMA, split-K=2 (f32-grade, feeds hashing)
    k_zero<<<2048, 256, 0, stream>>>(qkb);
    k_mgemm2_sk<<<1024, 256, 0, stream>>>(
        (const ushort*)xnh1, (const ushort*)xnh2,
        (const ushort*)(wqh1 + WQ), (const ushort*)(wqh2 + WQ),
        qkb, NTOK, 512, 512, 8, 512, 256);
    // v projection via f16 MFMA, scattered per head
    k_mgemm<1,0,0,0><<<512, 256, 0, stream>>>(
        (const ushort*)xnh1, (const ushort*)(wvh + WQ), nullptr, vb16, nullptr, NTOK, 512, 512, 8);
    k_qprep<<<8192, 256, 0, stream>>>(qkb, kn16, qnorm);
    k_hash<<<1024, 256, 0, stream>>>(qkb, rot + (long)l * 8192, buckets);
    k_sort<<<128, 256, 0, stream>>>(buckets, stx);
    k_attn_mfma<<<4096, 256, 0, stream>>>((const ushort*)kn16, qnorm, (const ushort*)vb16,
                                          stx, o16, lg);
    k_combine<<<NTOK, 256, 0, stream>>>(o16, lg, att16);
    // wo projection: f16 MFMA split-K=2, atomic residual into x1
    k_mgemm_sk<1><<<1024, 256, 0, stream>>>(
        (const ushort*)att16, (const ushort*)(woh + WQ), bo + l * 512, x1,
        NTOK, 512, 512, 8, 512, 256);
    // FFN via f16 MFMA
    k_ln<0><<<NTOK, 256, 0, stream>>>(x1, lnF_g + l * 512, lnF_b + l * 512, xnh1, nullptr);
    k_mgemm<0,1,1,0><<<2048, 256, 0, stream>>>(
        (const ushort*)xnh1, (const ushort*)(w1h + (long)l * 1048576),
        b1 + (long)l * 2048, h1h, nullptr, NTOK, 2048, 512, 32);
    k_mgemm_sk<1><<<2048, 256, 0, stream>>>(
        (const ushort*)h1h, (const ushort*)(w2h + (long)l * 1048576),
        b2 + l * 512, x2, NTOK, 512, 2048, 8, 512, 512);
  }
  // final linear: split-f16 (N padded to 128, real 88)
  k_halfcvt<<<NTOK, 256, 0, stream>>>(x1, x2, xnh1, xnh2);
  k_mgemm2<0,1,0,1><<<128, 256, 0, stream>>>(
      (const ushort*)xnh1, (const ushort*)xnh2, (const ushort*)linh1, (const ushort*)linh2,
      lin_b, (float*)d_out, NTOK, 128, 512, 2, 88);
}

// Round 9
// 1693.034 us; speedup vs baseline: 1.1440x; 1.1029x over previous
//
#include <hip/hip_runtime.h>
#include <hip/hip_fp16.h>
#include <cstdint>

#define T_LEN 2048
#define NTOK  4096      // B*T
#define NHASH 8
#define SELF_VAL -5e4f
#define SPLIT_S 2048.f
#define SPLIT_IS (1.f/2048.f)
#define TOKN 2097152L   // NTOK*512

typedef __attribute__((ext_vector_type(8))) short short8v;
typedef __attribute__((ext_vector_type(8))) _Float16 half8v;
typedef __attribute__((ext_vector_type(4))) float f32x4;
typedef __attribute__((ext_vector_type(4))) unsigned short ushort4v;

__device__ inline void split16(float v, __half& h1, __half& h2) {
  h1 = __float2half(v);
  h2 = __float2half((v - __half2float(h1)) * SPLIT_S);
}

// ---------------------------------------------------------------- im2col split-f16 (conv k=3 pad=1), K padded to 704
__global__ __launch_bounds__(256) void k_im2col2(
    const float* __restrict__ spec, __half* __restrict__ c1, __half* __restrict__ c2) {
  int m = blockIdx.x; int b = m >> 11, t = m & 2047;
  for (int c = threadIdx.x; c < 704; c += 256) {
    float v = 0.f;
    if (c < 687) {
      int k = (c >= 458) ? 2 : (c >= 229 ? 1 : 0);
      int i = c - k * 229;
      int tt = t + k - 1;
      if (tt >= 0 && tt < T_LEN) v = spec[((long)b * T_LEN + tt) * 229 + i];
    }
    __half h1, h2; split16(v, h1, h2);
    c1[(long)m * 704 + c] = h1; c2[(long)m * 704 + c] = h2;
  }
}

__global__ __launch_bounds__(256) void k_wconv2(
    const float* __restrict__ w, __half* __restrict__ d1, __half* __restrict__ d2) {
  int o = blockIdx.x;
  for (int c = threadIdx.x; c < 704; c += 256) {
    float v = 0.f;
    if (c < 687) {
      int k = (c >= 458) ? 2 : (c >= 229 ? 1 : 0);
      int i = c - k * 229;
      v = w[((long)o * 229 + i) * 3 + k];
    }
    __half h1, h2; split16(v, h1, h2);
    d1[(long)o * 704 + c] = h1; d2[(long)o * 704 + c] = h2;
  }
}

__global__ __launch_bounds__(256) void k_pe(
    const float* __restrict__ pe_row, const float* __restrict__ pe_col,
    float* __restrict__ x1, float* __restrict__ x2) {
  int m = blockIdx.x, t = m & 2047;
  for (int o = threadIdx.x; o < 512; o += 256) {
    long idx = (long)m * 512 + o;
    float v = x1[idx] + ((o < 256) ? pe_row[(t >> 6) * 256 + o]
                                   : pe_col[(t & 63) * 256 + (o - 256)]);
    x1[idx] = v; x2[idx] = v;
  }
}

// ---------------------------------------------------------------- layernorm; SPLIT: also emit scaled f16 correction
template<int SPLIT>
__global__ __launch_bounds__(256) void k_ln(
    const float* __restrict__ x, const float* __restrict__ g,
    const float* __restrict__ bb, __half* __restrict__ o1, __half* __restrict__ o2) {
  int row = blockIdx.x, tid = threadIdx.x;
  const float* xr = x + (long)row * 512;
  float v0 = xr[tid], v1 = xr[tid + 256];
  float s1 = v0 + v1, s2 = v0 * v0 + v1 * v1;
  #pragma unroll
  for (int off = 1; off < 64; off <<= 1) { s1 += __shfl_xor(s1, off); s2 += __shfl_xor(s2, off); }
  __shared__ float r1[4], r2[4];
  int w = tid >> 6, lane = tid & 63;
  if (lane == 0) { r1[w] = s1; r2[w] = s2; }
  __syncthreads();
  float S1 = r1[0] + r1[1] + r1[2] + r1[3];
  float S2 = r2[0] + r2[1] + r2[2] + r2[3];
  float mean = S1 * (1.f / 512.f);
  float var  = S2 * (1.f / 512.f) - mean * mean;
  float rstd = 1.f / sqrtf(var + 1e-5f);
  float a0 = (v0 - mean) * rstd * g[tid] + bb[tid];
  float a1 = (v1 - mean) * rstd * g[tid + 256] + bb[tid + 256];
  if (SPLIT) {
    __half h1, h2;
    split16(a0, h1, h2); o1[(long)row * 512 + tid] = h1; o2[(long)row * 512 + tid] = h2;
    split16(a1, h1, h2); o1[(long)row * 512 + tid + 256] = h1; o2[(long)row * 512 + tid + 256] = h2;
  } else {
    o1[(long)row * 512 + tid]       = __float2half(a0);
    o1[(long)row * 512 + tid + 256] = __float2half(a1);
  }
}

// 0.5*(x1+x2) -> split f16
__global__ __launch_bounds__(256) void k_halfcvt(
    const float* __restrict__ x1, const float* __restrict__ x2,
    __half* __restrict__ a1, __half* __restrict__ a2) {
  long idx = (long)blockIdx.x * 512 + threadIdx.x;
  #pragma unroll
  for (int rep = 0; rep < 2; ++rep, idx += 256) {
    float v = 0.5f * (x1[idx] + x2[idx]);
    __half h1, h2; split16(v, h1, h2);
    a1[idx] = h1; a2[idx] = h2;
  }
}

// ---------------------------------------------------------------- split-f16 MFMA GEMM (f32-grade): conv/lin (no split-K)
template<int MAP, int BIAS, int RELU, int NG>
__global__ __launch_bounds__(256) void k_mgemm2(
    const ushort* __restrict__ A1, const ushort* __restrict__ A2,
    const ushort* __restrict__ B1, const ushort* __restrict__ B2,
    const float* __restrict__ bias, float* __restrict__ C,
    int M, int N, int K, int ncol, int Nreal) {
  __shared__ ushort As1[64 * 40], As2[64 * 40], Bs1[64 * 40], Bs2[64 * 40];
  int tid = threadIdx.x;
  int nwg = gridDim.x, q8 = nwg >> 3, wg = blockIdx.x;
  int swz = (wg & 7) * q8 + (wg >> 3);
  int m0 = (swz / ncol) * 64, n0 = (swz % ncol) * 64;
  int wid = tid >> 6, lane = tid & 63;
  int wr = wid >> 1, wc = wid & 1;
  int r = lane & 15, kg = lane >> 4;
  int ar = tid >> 2, ac = tid & 3;
  f32x4 accM[2][2] = {}, accC[2][2] = {};
  for (int k0 = 0; k0 < K; k0 += 32) {
    __syncthreads();
    *(short8v*)&As1[ar * 40 + ac * 8] = *(const short8v*)(A1 + (long)(m0 + ar) * K + k0 + ac * 8);
    *(short8v*)&As2[ar * 40 + ac * 8] = *(const short8v*)(A2 + (long)(m0 + ar) * K + k0 + ac * 8);
    *(short8v*)&Bs1[ar * 40 + ac * 8] = *(const short8v*)(B1 + (long)(n0 + ar) * K + k0 + ac * 8);
    *(short8v*)&Bs2[ar * 40 + ac * 8] = *(const short8v*)(B2 + (long)(n0 + ar) * K + k0 + ac * 8);
    __syncthreads();
    half8v a1[2], a2[2], b1[2], b2[2];
    #pragma unroll
    for (int i = 0; i < 2; ++i) {
      a1[i] = *(const half8v*)&As1[(wr * 32 + i * 16 + r) * 40 + kg * 8];
      a2[i] = *(const half8v*)&As2[(wr * 32 + i * 16 + r) * 40 + kg * 8];
    }
    #pragma unroll
    for (int j = 0; j < 2; ++j) {
      b1[j] = *(const half8v*)&Bs1[(wc * 32 + j * 16 + r) * 40 + kg * 8];
      b2[j] = *(const half8v*)&Bs2[(wc * 32 + j * 16 + r) * 40 + kg * 8];
    }
    #pragma unroll
    for (int i = 0; i < 2; ++i)
      #pragma unroll
      for (int j = 0; j < 2; ++j) {
        accM[i][j] = __builtin_amdgcn_mfma_f32_16x16x32_f16(a1[i], b1[j], accM[i][j], 0, 0, 0);
        accC[i][j] = __builtin_amdgcn_mfma_f32_16x16x32_f16(a1[i], b2[j], accC[i][j], 0, 0, 0);
        accC[i][j] = __builtin_amdgcn_mfma_f32_16x16x32_f16(a2[i], b1[j], accC[i][j], 0, 0, 0);
      }
  }
  #pragma unroll
  for (int i = 0; i < 2; ++i) {
    int mb = m0 + wr * 32 + i * 16 + kg * 4;
    #pragma unroll
    for (int j = 0; j < 2; ++j) {
      int n = n0 + wc * 32 + j * 16 + r;
      if (NG && n >= Nreal) continue;
      float bv = BIAS ? bias[n] : 0.f;
      #pragma unroll
      for (int q = 0; q < 4; ++q) {
        float v = accM[i][j][q] + accC[i][j][q] * SPLIT_IS + bv;
        if (RELU) v = fmaxf(v, 0.f);
        long idx;
        if (MAP == 1) {
          int m = mb + q;
          int b = m >> 11, t = m & 2047, hh = n >> 6, dd = n & 63;
          idx = (((long)(b * 8 + hh)) * T_LEN + t) * 64 + dd;
        } else {
          idx = (long)(mb + q) * Nreal + n;
        }
        C[idx] = v;
      }
    }
  }
}

// ---------------------------------------------------------------- split-f16 MFMA GEMM, split-K partials (qk)
// stores P[s][m][n] row-major, no atomics.
__global__ __launch_bounds__(256) void k_mgemm2_skp(
    const ushort* __restrict__ A1, const ushort* __restrict__ A2,
    const ushort* __restrict__ B1, const ushort* __restrict__ B2,
    float* __restrict__ P, int M, int N, int K, int ncol, int nbase, int Kc) {
  __shared__ ushort As1[64 * 40], As2[64 * 40], Bs1[64 * 40], Bs2[64 * 40];
  int tid = threadIdx.x;
  int s = blockIdx.x / nbase, wg = blockIdx.x % nbase;
  int q8 = nbase >> 3;
  int swz = (wg & 7) * q8 + (wg >> 3);
  int m0 = (swz / ncol) * 64, n0 = (swz % ncol) * 64;
  int wid = tid >> 6, lane = tid & 63;
  int wr = wid >> 1, wc = wid & 1;
  int r = lane & 15, kg = lane >> 4;
  int ar = tid >> 2, ac = tid & 3;
  f32x4 accM[2][2] = {}, accC[2][2] = {};
  int kend = s * Kc + Kc;
  for (int k0 = s * Kc; k0 < kend; k0 += 32) {
    __syncthreads();
    *(short8v*)&As1[ar * 40 + ac * 8] = *(const short8v*)(A1 + (long)(m0 + ar) * K + k0 + ac * 8);
    *(short8v*)&As2[ar * 40 + ac * 8] = *(const short8v*)(A2 + (long)(m0 + ar) * K + k0 + ac * 8);
    *(short8v*)&Bs1[ar * 40 + ac * 8] = *(const short8v*)(B1 + (long)(n0 + ar) * K + k0 + ac * 8);
    *(short8v*)&Bs2[ar * 40 + ac * 8] = *(const short8v*)(B2 + (long)(n0 + ar) * K + k0 + ac * 8);
    __syncthreads();
    half8v a1[2], a2[2], b1[2], b2[2];
    #pragma unroll
    for (int i = 0; i < 2; ++i) {
      a1[i] = *(const half8v*)&As1[(wr * 32 + i * 16 + r) * 40 + kg * 8];
      a2[i] = *(const half8v*)&As2[(wr * 32 + i * 16 + r) * 40 + kg * 8];
    }
    #pragma unroll
    for (int j = 0; j < 2; ++j) {
      b1[j] = *(const half8v*)&Bs1[(wc * 32 + j * 16 + r) * 40 + kg * 8];
      b2[j] = *(const half8v*)&Bs2[(wc * 32 + j * 16 + r) * 40 + kg * 8];
    }
    #pragma unroll
    for (int i = 0; i < 2; ++i)
      #pragma unroll
      for (int j = 0; j < 2; ++j) {
        accM[i][j] = __builtin_amdgcn_mfma_f32_16x16x32_f16(a1[i], b1[j], accM[i][j], 0, 0, 0);
        accC[i][j] = __builtin_amdgcn_mfma_f32_16x16x32_f16(a1[i], b2[j], accC[i][j], 0, 0, 0);
        accC[i][j] = __builtin_amdgcn_mfma_f32_16x16x32_f16(a2[i], b1[j], accC[i][j], 0, 0, 0);
      }
  }
  long base = (long)s * M * N;
  #pragma unroll
  for (int i = 0; i < 2; ++i) {
    int mb = m0 + wr * 32 + i * 16 + kg * 4;
    #pragma unroll
    for (int j = 0; j < 2; ++j) {
      int n = n0 + wc * 32 + j * 16 + r;
      #pragma unroll
      for (int q = 0; q < 4; ++q)
        P[base + (long)(mb + q) * N + n] = accM[i][j][q] + accC[i][j][q] * SPLIT_IS;
    }
  }
}

// reduce 2 qk partials + scatter to head layout [b,h,t,d]
__global__ __launch_bounds__(256) void k_reduceq(
    const float* __restrict__ P, float* __restrict__ qkb) {
  long i = ((long)blockIdx.x * 256 + threadIdx.x) * 4;
  float4 a = *(const float4*)(P + i);
  float4 b = *(const float4*)(P + TOKN + i);
  a.x += b.x; a.y += b.y; a.z += b.z; a.w += b.w;
  long m = i >> 9;
  int n = (int)(i & 511);
  int bb = (int)(m >> 11), t = (int)(m & 2047), hh = n >> 6, dd = n & 63;
  long idx = (((long)(bb * 8 + hh)) * T_LEN + t) * 64 + dd;
  *(float4*)(qkb + idx) = a;
}

// ---------------------------------------------------------------- f16 MFMA GEMM (v/FFN1), 64x64 tile, BK=32
template<int MAP, int BIAS, int GELU, int RES>
__global__ __launch_bounds__(256) void k_mgemm(
    const ushort* __restrict__ A, const ushort* __restrict__ Bt,
    const float* __restrict__ bias, __half* __restrict__ Ch,
    float* __restrict__ Cf, int M, int N, int K, int ncol) {
  __shared__ ushort As[64 * 40];
  __shared__ ushort Bs[64 * 40];
  int tid = threadIdx.x;
  int nwg = gridDim.x, q8 = nwg >> 3, wg = blockIdx.x;
  int swz = (wg & 7) * q8 + (wg >> 3);
  int m0 = (swz / ncol) * 64, n0 = (swz % ncol) * 64;
  int wid = tid >> 6, lane = tid & 63;
  int wr = wid >> 1, wc = wid & 1;
  int r = lane & 15, kg = lane >> 4;
  int ar = tid >> 2, ac = tid & 3;
  f32x4 acc[2][2] = {};
  for (int k0 = 0; k0 < K; k0 += 32) {
    __syncthreads();
    *(short8v*)&As[ar * 40 + ac * 8] =
        *(const short8v*)(A + (long)(m0 + ar) * K + k0 + ac * 8);
    *(short8v*)&Bs[ar * 40 + ac * 8] =
        *(const short8v*)(Bt + (long)(n0 + ar) * K + k0 + ac * 8);
    __syncthreads();
    half8v af[2], bf[2];
    #pragma unroll
    for (int i = 0; i < 2; ++i)
      af[i] = *(const half8v*)&As[(wr * 32 + i * 16 + r) * 40 + kg * 8];
    #pragma unroll
    for (int j = 0; j < 2; ++j)
      bf[j] = *(const half8v*)&Bs[(wc * 32 + j * 16 + r) * 40 + kg * 8];
    #pragma unroll
    for (int i = 0; i < 2; ++i)
      #pragma unroll
      for (int j = 0; j < 2; ++j)
        acc[i][j] = __builtin_amdgcn_mfma_f32_16x16x32_f16(af[i], bf[j], acc[i][j], 0, 0, 0);
  }
  #pragma unroll
  for (int i = 0; i < 2; ++i) {
    int mb = m0 + wr * 32 + i * 16 + kg * 4;
    #pragma unroll
    for (int j = 0; j < 2; ++j) {
      int n = n0 + wc * 32 + j * 16 + r;
      float bv = BIAS ? bias[n] : 0.f;
      #pragma unroll
      for (int q = 0; q < 4; ++q) {
        float v = acc[i][j][q] + bv;
        if (GELU) v = 0.5f * v * (1.f + erff(v * 0.70710678118654752f));
        long idx;
        if (MAP == 1) {
          int m = mb + q;
          int b = m >> 11, t = m & 2047, hh = n >> 6, dd = n & 63;
          idx = (((long)(b * 8 + hh)) * T_LEN + t) * 64 + dd;
        } else {
          idx = (long)(mb + q) * N + n;
        }
        if (RES) Cf[idx] += v;
        else Ch[idx] = __float2half(v);
      }
    }
  }
}

// ---------------------------------------------------------------- f16 MFMA GEMM split-K partials (wo/FFN2)
__global__ __launch_bounds__(256) void k_mgemm_skp(
    const ushort* __restrict__ A, const ushort* __restrict__ Bt,
    float* __restrict__ P, int M, int N, int K, int ncol, int nbase, int Kc) {
  __shared__ ushort As[64 * 40];
  __shared__ ushort Bs[64 * 40];
  int tid = threadIdx.x;
  int s = blockIdx.x / nbase, wg = blockIdx.x % nbase;
  int q8 = nbase >> 3;
  int swz = (wg & 7) * q8 + (wg >> 3);
  int m0 = (swz / ncol) * 64, n0 = (swz % ncol) * 64;
  int wid = tid >> 6, lane = tid & 63;
  int wr = wid >> 1, wc = wid & 1;
  int r = lane & 15, kg = lane >> 4;
  int ar = tid >> 2, ac = tid & 3;
  f32x4 acc[2][2] = {};
  int kend = s * Kc + Kc;
  for (int k0 = s * Kc; k0 < kend; k0 += 32) {
    __syncthreads();
    *(short8v*)&As[ar * 40 + ac * 8] =
        *(const short8v*)(A + (long)(m0 + ar) * K + k0 + ac * 8);
    *(short8v*)&Bs[ar * 40 + ac * 8] =
        *(const short8v*)(Bt + (long)(n0 + ar) * K + k0 + ac * 8);
    __syncthreads();
    half8v af[2], bf[2];
    #pragma unroll
    for (int i = 0; i < 2; ++i)
      af[i] = *(const half8v*)&As[(wr * 32 + i * 16 + r) * 40 + kg * 8];
    #pragma unroll
    for (int j = 0; j < 2; ++j)
      bf[j] = *(const half8v*)&Bs[(wc * 32 + j * 16 + r) * 40 + kg * 8];
    #pragma unroll
    for (int i = 0; i < 2; ++i)
      #pragma unroll
      for (int j = 0; j < 2; ++j)
        acc[i][j] = __builtin_amdgcn_mfma_f32_16x16x32_f16(af[i], bf[j], acc[i][j], 0, 0, 0);
  }
  long base = (long)s * M * N;
  #pragma unroll
  for (int i = 0; i < 2; ++i) {
    int mb = m0 + wr * 32 + i * 16 + kg * 4;
    #pragma unroll
    for (int j = 0; j < 2; ++j) {
      int n = n0 + wc * 32 + j * 16 + r;
      #pragma unroll
      for (int q = 0; q < 4; ++q)
        P[base + (long)(mb + q) * N + n] = acc[i][j][q];
    }
  }
}

// reduce S partials + bias + residual into dst (float4 stride)
template<int S>
__global__ __launch_bounds__(256) void k_reduce_br(
    const float* __restrict__ P, const float* __restrict__ bias,
    float* __restrict__ dst, long total, int N) {
  long i = ((long)blockIdx.x * 256 + threadIdx.x) * 4;
  float4 a = *(const float4*)(P + i);
  #pragma unroll
  for (int s = 1; s < S; ++s) {
    float4 b = *(const float4*)(P + (long)s * total + i);
    a.x += b.x; a.y += b.y; a.z += b.z; a.w += b.w;
  }
  int n = (int)(i % N);
  a.x += bias[n]; a.y += bias[n + 1]; a.z += bias[n + 2]; a.w += bias[n + 3];
  float4 c = *(const float4*)(dst + i);
  a.x += c.x; a.y += c.y; a.z += c.z; a.w += c.w;
  *(float4*)(dst + i) = a;
}

// tiled transpose + f32->f16, z = layer
__global__ __launch_bounds__(256) void k_tcvt_z(
    const float* __restrict__ src0, __half* __restrict__ dst0, int R, int C) {
  __shared__ float tile[32][33];
  long lo = (long)blockIdx.z * R * C;
  const float* src = src0 + lo;
  __half* dst = dst0 + lo;
  int c0 = blockIdx.x * 32, r0 = blockIdx.y * 32;
  int tx = threadIdx.x & 31, ty = threadIdx.x >> 5;
  #pragma unroll
  for (int i = 0; i < 4; ++i)
    tile[ty + i * 8][tx] = src[(long)(r0 + ty + i * 8) * C + c0 + tx];
  __syncthreads();
  #pragma unroll
  for (int i = 0; i < 4; ++i)
    dst[(long)(c0 + ty + i * 8) * R + r0 + tx] = __float2half(tile[tx][ty + i * 8]);
}

// tiled transpose + split pair, z = layer
__global__ __launch_bounds__(256) void k_tcvt2_z(
    const float* __restrict__ src0, __half* __restrict__ d10, __half* __restrict__ d20,
    int R, int C) {
  __shared__ float tile[32][33];
  long lo = (long)blockIdx.z * R * C;
  const float* src = src0 + lo;
  __half* d1 = d10 + lo; __half* d2 = d20 + lo;
  int c0 = blockIdx.x * 32, r0 = blockIdx.y * 32;
  int tx = threadIdx.x & 31, ty = threadIdx.x >> 5;
  #pragma unroll
  for (int i = 0; i < 4; ++i)
    tile[ty + i * 8][tx] = src[(long)(r0 + ty + i * 8) * C + c0 + tx];
  __syncthreads();
  #pragma unroll
  for (int i = 0; i < 4; ++i) {
    float v = tile[tx][ty + i * 8];
    __half h1, h2; split16(v, h1, h2);
    long o = (long)(c0 + ty + i * 8) * R + r0 + tx;
    d1[o] = h1; d2[o] = h2;
  }
}

// tiled transpose + split pair, col-padded (final lin weight)
__global__ __launch_bounds__(256) void k_tcvt2(
    const float* __restrict__ src, __half* __restrict__ d1, __half* __restrict__ d2,
    int R, int C) {
  __shared__ float tile[32][33];
  int c0 = blockIdx.x * 32, r0 = blockIdx.y * 32;
  int tx = threadIdx.x & 31, ty = threadIdx.x >> 5;
  #pragma unroll
  for (int i = 0; i < 4; ++i) {
    int c = c0 + tx;
    tile[ty + i * 8][tx] = (c < C) ? src[(long)(r0 + ty + i * 8) * C + c] : 0.f;
  }
  __syncthreads();
  #pragma unroll
  for (int i = 0; i < 4; ++i) {
    float v = tile[tx][ty + i * 8];
    __half h1, h2; split16(v, h1, h2);
    long o = (long)(c0 + ty + i * 8) * R + r0 + tx;
    d1[o] = h1; d2[o] = h2;
  }
}

// ---------------------------------------------------------------- LSH hashing (f32) + fused qprep
__global__ __launch_bounds__(256) void k_hash(
    const float* __restrict__ qk, const float* __restrict__ rot,
    int* __restrict__ buckets, __half* __restrict__ kn, float* __restrict__ qnorm) {
  int bhid = blockIdx.x >> 6; int t0 = (blockIdx.x & 63) * 32;
  __shared__ float qrow[32][64];
  __shared__ float rl[64][8][20];
  for (int idx = threadIdx.x; idx < 32 * 64; idx += 256) {
    int tok = idx >> 6, f = idx & 63;
    qrow[tok][f] = qk[((long)bhid * T_LEN + t0 + tok) * 64 + f];
  }
  for (int idx = threadIdx.x; idx < 64 * 128; idx += 256) {
    int f = idx >> 7, rem = idx & 127, hh = rem >> 4, ii = rem & 15;
    rl[f][hh][ii] = rot[idx];
  }
  __syncthreads();
  int tid = threadIdx.x;
  // fused qprep: 8 threads per row
  {
    int tok2 = tid >> 3, s8 = tid & 7;
    float vv8[8]; float ss = 0.f;
    #pragma unroll
    for (int j = 0; j < 8; ++j) { vv8[j] = qrow[tok2][s8 * 8 + j]; ss += vv8[j] * vv8[j]; }
    ss += __shfl_xor(ss, 1); ss += __shfl_xor(ss, 2); ss += __shfl_xor(ss, 4);
    float nrm = fmaxf(sqrtf(ss), 1e-12f);
    float inr = 1.f / nrm;
    short8v pk;
    #pragma unroll
    for (int j = 0; j < 8; ++j) pk[j] = (short)__half_as_ushort(__float2half(vv8[j] * inr));
    long rowg = (long)bhid * T_LEN + t0 + tok2;
    *(short8v*)(&((ushort*)kn)[rowg * 64 + s8 * 8]) = pk;
    if (s8 == 0) qnorm[rowg] = nrm;
  }
  // hash buckets
  int tok = tid >> 3, h = tid & 7;
  float acc[16] = {};
  for (int f = 0; f < 64; ++f) {
    float qv = qrow[tok][f];
    #pragma unroll
    for (int i = 0; i < 16; ++i) acc[i] += qv * rl[f][h][i];
  }
  float best = acc[0]; int bi = 0;
  #pragma unroll
  for (int i = 1; i < 16; ++i) if (acc[i] > best) { best = acc[i]; bi = i; }
  #pragma unroll
  for (int i = 0; i < 16; ++i) if (-acc[i] > best) { best = -acc[i]; bi = 16 + i; }
  buckets[((long)bhid * 8 + h) * T_LEN + t0 + tok] = bi;
}

// ---------------------------------------------------------------- stable counting sort
__global__ __launch_bounds__(256) void k_sort(
    const int* __restrict__ buckets, int* __restrict__ st) {
  int bh = blockIdx.x >> 3, h = blockIdx.x & 7;
  const int* bk = buckets + ((long)bh * 8 + h) * T_LEN;
  __shared__ unsigned char lb[2048];
  __shared__ int hist[32], cnt[32];
  __shared__ int whist[4][32];
  if (threadIdx.x < 32) hist[threadIdx.x] = 0;
  __syncthreads();
  for (int p = threadIdx.x; p < 2048; p += 256) {
    int v = bk[p]; lb[p] = (unsigned char)v; atomicAdd(&hist[v], 1);
  }
  __syncthreads();
  if (threadIdx.x == 0) {
    int run = 0;
    for (int i = 0; i < 32; ++i) { cnt[i] = run; run += hist[i]; }
  }
  __syncthreads();
  int lane = threadIdx.x & 63, w = threadIdx.x >> 6;
  unsigned long long mlt = (1ull << lane) - 1ull;
  int* outp = st + (long)bh * (NHASH * T_LEN) + h * T_LEN;
  for (int tile = 0; tile < 8; ++tile) {
    int p = tile * 256 + threadIdx.x;
    int myb = lb[p];
    int wrank = 0;
    for (int bv = 0; bv < 32; ++bv) {
      unsigned long long mm = __ballot(myb == bv);
      if (myb == bv) wrank = __popcll(mm & mlt);
      if (lane == bv) whist[w][bv] = __popcll(mm);
    }
    __syncthreads();
    int off = cnt[myb];
    for (int w2 = 0; w2 < w; ++w2) off += whist[w2][myb];
    outp[off + wrank] = p;
    __syncthreads();
    if (threadIdx.x < 32)
      cnt[threadIdx.x] += whist[0][threadIdx.x] + whist[1][threadIdx.x] +
                          whist[2][threadIdx.x] + whist[3][threadIdx.x];
    __syncthreads();
  }
}

// ---------------------------------------------------------------- MFMA chunked attention (o out f16)
// Ps aliases Kb; deferred softmax normalization (scale at output).
__global__ __launch_bounds__(256) void k_attn_mfma(
    const ushort* __restrict__ kn, const float* __restrict__ qnorm,
    const ushort* __restrict__ vv, const int* __restrict__ st,
    __half* __restrict__ o, float* __restrict__ lg) {
  __shared__ ushort KbPs[128 * 72];
  __shared__ ushort Vt[64 * 136];
  __shared__ int   kpos[128];
  __shared__ float qn[64];
  __shared__ float invs[64];
  int bh = blockIdx.x >> 8, c = blockIdx.x & 255;
  int h = c >> 5, cp = (c + 255) & 255;
  int tid = threadIdx.x, lane = tid & 63, w = tid >> 6;
  int r16 = lane & 15, kg = lane >> 4;
  const int* stb = st + (long)bh * (NHASH * T_LEN);
  if (tid < 128) kpos[tid] = stb[((tid < 64) ? c : cp) * 64 + (tid & 63)];
  __syncthreads();
  if (tid < 64) qn[tid] = qnorm[bh * T_LEN + kpos[tid]];
  const ushort* knb = kn + (long)bh * T_LEN * 64;
  const ushort* vvb = vv + (long)bh * T_LEN * 64;
  for (int idx = tid; idx < 1024; idx += 256) {
    int rr = idx >> 3, p = idx & 7;
    *(short8v*)&KbPs[rr * 72 + p * 8] = *(const short8v*)(knb + (long)kpos[rr] * 64 + p * 8);
  }
  {
    int rr = (tid & 63) * 2;
    ushort a[16], b[16];
    *(short8v*)&a[0] = *(const short8v*)(vvb + (long)kpos[rr] * 64 + w * 16);
    *(short8v*)&a[8] = *(const short8v*)(vvb + (long)kpos[rr] * 64 + w * 16 + 8);
    *(short8v*)&b[0] = *(const short8v*)(vvb + (long)kpos[rr + 1] * 64 + w * 16);
    *(short8v*)&b[8] = *(const short8v*)(vvb + (long)kpos[rr + 1] * 64 + w * 16 + 8);
    #pragma unroll
    for (int i = 0; i < 16; ++i) {
      int d = w * 16 + i;
      *(unsigned int*)&Vt[d * 136 + rr] = (unsigned int)a[i] | ((unsigned int)b[i] << 16);
    }
  }
  __syncthreads();
  f32x4 sacc[8] = {};
  #pragma unroll
  for (int ks = 0; ks < 2; ++ks) {
    half8v bfq = *(const half8v*)&KbPs[(w * 16 + r16) * 72 + ks * 32 + kg * 8];
    #pragma unroll
    for (int i = 0; i < 8; ++i) {
      half8v af = *(const half8v*)&KbPs[(i * 16 + r16) * 72 + ks * 32 + kg * 8];
      sacc[i] = __builtin_amdgcn_mfma_f32_16x16x32_f16(af, bfq, sacc[i], 0, 0, 0);
    }
  }
  __syncthreads();   // Kb dead; overwrite with Ps
  int q = w * 16 + r16;
  int qposv = kpos[q];
  float sc = 0.125f * qn[q];
  float vals[8][4];
  float mx = -3.4e38f;
  #pragma unroll
  for (int f = 0; f < 8; ++f)
    #pragma unroll
    for (int e = 0; e < 4; ++e) {
      int kv = f * 16 + kg * 4 + e;
      float v = sacc[f][e] * sc;
      if (kpos[kv] == qposv) v = SELF_VAL;
      vals[f][e] = v;
      mx = fmaxf(mx, v);
    }
  mx = fmaxf(mx, __shfl_xor(mx, 16));
  mx = fmaxf(mx, __shfl_xor(mx, 32));
  float sm = 0.f;
  #pragma unroll
  for (int f = 0; f < 8; ++f)
    #pragma unroll
    for (int e = 0; e < 4; ++e) { vals[f][e] = __expf(vals[f][e] - mx); sm += vals[f][e]; }
  sm += __shfl_xor(sm, 16);
  sm += __shfl_xor(sm, 32);
  #pragma unroll
  for (int f = 0; f < 8; ++f) {
    ushort4v pw;
    #pragma unroll
    for (int e = 0; e < 4; ++e) pw[e] = __half_as_ushort(__float2half(vals[f][e]));
    *(ushort4v*)&KbPs[q * 136 + f * 16 + kg * 4] = pw;
  }
  if (kg == 0) {
    lg[((long)bh * 8 + h) * T_LEN + qposv] = mx + logf(sm);
    invs[q] = 1.f / sm;
  }
  __syncthreads();
  f32x4 oacc[4] = {};
  #pragma unroll
  for (int ks = 0; ks < 4; ++ks) {
    half8v vf = *(const half8v*)&Vt[(w * 16 + r16) * 136 + ks * 32 + kg * 8];
    #pragma unroll
    for (int i = 0; i < 4; ++i) {
      half8v pf = *(const half8v*)&KbPs[(i * 16 + r16) * 136 + ks * 32 + kg * 8];
      oacc[i] = __builtin_amdgcn_mfma_f32_16x16x32_f16(pf, vf, oacc[i], 0, 0, 0);
    }
  }
  long ob = ((long)bh * 8 + h) * T_LEN;
  int d = w * 16 + r16;
  #pragma unroll
  for (int i = 0; i < 4; ++i)
    #pragma unroll
    for (int e = 0; e < 4; ++e) {
      int qq = i * 16 + kg * 4 + e;
      o[(ob + kpos[qq]) * 64 + d] = __float2half(oacc[i][e] * invs[qq]);
    }
}

// ---------------------------------------------------------------- combine hash rounds (f16 in/out)
__global__ __launch_bounds__(256) void k_combine(
    const __half* __restrict__ o, const float* __restrict__ lg, __half* __restrict__ att) {
  int m = blockIdx.x; int b = m >> 11, t = m & 2047;
  int head = threadIdx.x >> 5, d0 = (threadIdx.x & 31) * 2;
  int bh = b * 8 + head;
  const float* lgp = lg + (long)bh * 8 * T_LEN + t;
  float l[8], mx = -3.4e38f;
  #pragma unroll
  for (int hh = 0; hh < 8; ++hh) { l[hh] = lgp[(long)hh * T_LEN]; mx = fmaxf(mx, l[hh]); }
  float sm = 0.f;
  #pragma unroll
  for (int hh = 0; hh < 8; ++hh) { l[hh] = expf(l[hh] - mx); sm += l[hh]; }
  float inv = 1.f / sm;
  float a0 = 0.f, a1 = 0.f;
  #pragma unroll
  for (int hh = 0; hh < 8; ++hh) {
    const __half* op = o + (((long)bh * 8 + hh) * T_LEN + t) * 64 + d0;
    float w_ = l[hh] * inv;
    a0 += w_ * __half2float(op[0]); a1 += w_ * __half2float(op[1]);
  }
  unsigned int u = (unsigned int)__half_as_ushort(__float2half(a0)) |
                   ((unsigned int)__half_as_ushort(__float2half(a1)) << 16);
  *(unsigned int*)&att[(long)m * 512 + head * 64 + d0] = u;
}

// ---------------------------------------------------------------- host
extern "C" void kernel_launch(void* const* d_in, const int* in_sizes, int n_in,
                              void* d_out, int out_size, void* d_ws, size_t ws_size,
                              hipStream_t stream) {
  const float* spec   = (const float*)d_in[0];
  const float* conv_w = (const float*)d_in[1];
  const float* conv_b = (const float*)d_in[2];
  const float* pe_row = (const float*)d_in[3];
  const float* pe_col = (const float*)d_in[4];
  const float* lnA_g  = (const float*)d_in[5];
  const float* lnA_b  = (const float*)d_in[6];
  const float* wqk    = (const float*)d_in[7];
  const float* wv     = (const float*)d_in[8];
  const float* wo     = (const float*)d_in[9];
  const float* bo     = (const float*)d_in[10];
  const float* lnF_g  = (const float*)d_in[11];
  const float* lnF_b  = (const float*)d_in[12];
  const float* w1     = (const float*)d_in[13];
  const float* b1     = (const float*)d_in[14];
  const float* w2     = (const float*)d_in[15];
  const float* b2     = (const float*)d_in[16];
  const float* lin_w  = (const float*)d_in[17];
  const float* lin_b  = (const float*)d_in[18];
  const float* rot    = (const float*)d_in[19];

  float* ws = (float*)d_ws;
  const long TOKF = TOKN;                          // 2,097,152
  float* x1   = ws;
  float* x2   = x1 + TOKF;
  float* qkb  = x2 + TOKF;
  float* lg   = qkb + TOKF;                        // 262,144
  __half* o16 = (__half*)(lg + 262144);            // 16,777,216 halves (33.5 MB)
  float* psum = (float*)o16;                       // alias: 8,388,608 f32 partial scratch
  int*   stx  = (int*)(o16 + (long)16777216);
  int*   buckets = stx + 262144;
  float* base = (float*)(buckets + 262144);
  __half* xnh1  = (__half*)base;
  __half* xnh2  = (__half*)(base + TOKF / 2);
  __half* att16 = (__half*)(base + 2 * (TOKF / 2));
  __half* vb16  = (__half*)(base + 3 * (TOKF / 2));
  __half* kn16  = (__half*)(base + 4 * (TOKF / 2));
  float* qnorm  = base + 5 * (TOKF / 2);
  __half* h1h   = (__half*)(qnorm + 32768);        // 8,388,608 halves
  __half* colh1 = h1h;                             // alias (conv first)
  __half* colh2 = colh1 + (long)4096 * 704;
  float* wall   = (float*)(h1h + (long)8388608);
  __half* w1h   = (__half*)wall;
  __half* w2h   = (__half*)(wall + 4194304);
  __half* wqh1  = (__half*)(wall + 2 * 4194304);
  __half* wqh2  = (__half*)(wall + 2 * 4194304 + 1048576);
  __half* wvh   = (__half*)(wall + 2 * 4194304 + 2 * 1048576);
  __half* woh   = (__half*)(wall + 2 * 4194304 + 3 * 1048576);
  __half* cwh1  = (__half*)(wall + 2 * 4194304 + 4 * 1048576);
  __half* cwh2  = (__half*)(wall + 2 * 4194304 + 4 * 1048576 + 180224);
  __half* linh1 = (__half*)(wall + 2 * 4194304 + 4 * 1048576 + 2 * 180224);
  __half* linh2 = (__half*)(wall + 2 * 4194304 + 4 * 1048576 + 2 * 180224 + 32768);

  // ---- all weight conversions upfront (batched over layers) ----
  k_tcvt_z <<<dim3(64, 16, 8), 256, 0, stream>>>(w1,  w1h, 512, 2048);
  k_tcvt_z <<<dim3(16, 64, 8), 256, 0, stream>>>(w2,  w2h, 2048, 512);
  k_tcvt2_z<<<dim3(16, 16, 8), 256, 0, stream>>>(wqk, wqh1, wqh2, 512, 512);
  k_tcvt_z <<<dim3(16, 16, 8), 256, 0, stream>>>(wv,  wvh, 512, 512);
  k_tcvt_z <<<dim3(16, 16, 8), 256, 0, stream>>>(wo,  woh, 512, 512);
  k_wconv2 <<<512, 256, 0, stream>>>(conv_w, cwh1, cwh2);
  k_tcvt2  <<<dim3(4, 16), 256, 0, stream>>>(lin_w, linh1, linh2, 512, 88);

  // conv frontend: split-f16 MFMA GEMM (f32-grade)
  k_im2col2<<<NTOK, 256, 0, stream>>>(spec, colh1, colh2);
  k_mgemm2<0,1,1,0><<<512, 256, 0, stream>>>(
      (const ushort*)colh1, (const ushort*)colh2, (const ushort*)cwh1, (const ushort*)cwh2,
      conv_b, x1, NTOK, 512, 704, 8, 512);
  k_pe<<<NTOK, 256, 0, stream>>>(pe_row, pe_col, x1, x2);

  for (int l = 0; l < 8; ++l) {
    const long WQ = (long)l * 262144;
    k_ln<1><<<NTOK, 256, 0, stream>>>(x2, lnA_g + l * 512, lnA_b + l * 512, xnh1, xnh2);
    // qk projection: split-f16, split-K=2 partials -> reduce+scatter
    k_mgemm2_skp<<<1024, 256, 0, stream>>>(
        (const ushort*)xnh1, (const ushort*)xnh2,
        (const ushort*)(wqh1 + WQ), (const ushort*)(wqh2 + WQ),
        psum, NTOK, 512, 512, 8, 512, 256);
    k_reduceq<<<2048, 256, 0, stream>>>(psum, qkb);
    // v projection via f16 MFMA, scattered per head
    k_mgemm<1,0,0,0><<<512, 256, 0, stream>>>(
        (const ushort*)xnh1, (const ushort*)(wvh + WQ), nullptr, vb16, nullptr, NTOK, 512, 512, 8);
    // hash (+fused qprep)
    k_hash<<<1024, 256, 0, stream>>>(qkb, rot + (long)l * 8192, buckets, kn16, qnorm);
    k_sort<<<128, 256, 0, stream>>>(buckets, stx);
    k_attn_mfma<<<4096, 256, 0, stream>>>((const ushort*)kn16, qnorm, (const ushort*)vb16,
                                          stx, o16, lg);
    k_combine<<<NTOK, 256, 0, stream>>>(o16, lg, att16);
    // wo projection: split-K=2 partials -> reduce(+bias+residual into x1)
    k_mgemm_skp<<<1024, 256, 0, stream>>>(
        (const ushort*)att16, (const ushort*)(woh + WQ), psum, NTOK, 512, 512, 8, 512, 256);
    k_reduce_br<2><<<2048, 256, 0, stream>>>(psum, bo + l * 512, x1, TOKN, 512);
    // FFN
    k_ln<0><<<NTOK, 256, 0, stream>>>(x1, lnF_g + l * 512, lnF_b + l * 512, xnh1, nullptr);
    k_mgemm<0,1,1,0><<<2048, 256, 0, stream>>>(
        (const ushort*)xnh1, (const ushort*)(w1h + (long)l * 1048576),
        b1 + (long)l * 2048, h1h, nullptr, NTOK, 2048, 512, 32);
    k_mgemm_skp<<<1024, 256, 0, stream>>>(
        (const ushort*)h1h, (const ushort*)(w2h + (long)l * 1048576),
        psum, NTOK, 512, 2048, 8, 512, 1024);
    k_reduce_br<2><<<2048, 256, 0, stream>>>(psum, b2 + l * 512, x2, TOKN, 512);
  }
  // final linear: split-f16 (N padded to 128, real 88)
  k_halfcvt<<<NTOK, 256, 0, stream>>>(x1, x2, xnh1, xnh2);
  k_mgemm2<0,1,0,1><<<128, 256, 0, stream>>>(
      (const ushort*)xnh1, (const ushort*)xnh2, (const ushort*)linh1, (const ushort*)linh2,
      lin_b, (float*)d_out, NTOK, 128, 512, 2, 88);
}